// Round 5
// baseline (493.290 us; speedup 1.0000x reference)
//
#include <hip/hip_runtime.h>

// ---- problem constants ----
#define D_MODEL 1024
#define NHEAD   16
#define DK      64
#define BATCH   2
#define SEQ     2048

typedef __attribute__((ext_vector_type(8))) short bf16x8;
typedef __attribute__((ext_vector_type(4))) float f32x4;

#define QSCALE 0.18033688011f   // log2(e) / sqrt(64): folded into Q projection

__device__ __forceinline__ unsigned short f2b(float x) {
  unsigned u = __builtin_bit_cast(unsigned, x);
  u = (u + 0x7fffu + ((u >> 16) & 1u)) >> 16;   // RNE to bf16
  return (unsigned short)u;
}
// round-half-up bf16 (bias 2^-17 rel, error <= 2^-9 like RNE) -- 1 add
__device__ __forceinline__ unsigned short f2b_rhu(float x) {
  return (unsigned short)((__builtin_bit_cast(unsigned, x) + 0x8000u) >> 16);
}
// pack two fp32 -> two bf16 (round-half-up) in 3 VALU: add, add, v_perm
__device__ __forceinline__ int pk2(float a, float b) {
  unsigned ua = __builtin_bit_cast(unsigned, a) + 0x8000u;
  unsigned ub = __builtin_bit_cast(unsigned, b) + 0x8000u;
  return (int)__builtin_amdgcn_perm(ub, ua, 0x07060302u);  // [ub.hi16 : ua.hi16]
}

// ---- transpose + cast weights: w[in][out] fp32 -> wt[out][in] bf16 ----
__global__ __launch_bounds__(256) void wtrans_kernel(
    const float* __restrict__ wq, const float* __restrict__ wk,
    const float* __restrict__ wv, const float* __restrict__ wf,
    unsigned short* __restrict__ wqt, unsigned short* __restrict__ wkt,
    unsigned short* __restrict__ wvt, unsigned short* __restrict__ wft) {
  __shared__ float tile[64][65];
  const float* w; unsigned short* wt;
  switch (blockIdx.z) {
    case 0: w = wq; wt = wqt; break;
    case 1: w = wk; wt = wkt; break;
    case 2: w = wv; wt = wvt; break;
    default: w = wf; wt = wft; break;
  }
  int r0 = blockIdx.y * 64, c0 = blockIdx.x * 64;
  int t = threadIdx.x;
  for (int i = 0; i < 16; ++i) {
    int idx = t + i * 256; int r = idx >> 6, c = idx & 63;
    tile[r][c] = w[(size_t)(r0 + r) * D_MODEL + c0 + c];
  }
  __syncthreads();
  for (int i = 0; i < 16; ++i) {
    int idx = t + i * 256; int r = idx >> 6, c = idx & 63;
    wt[(size_t)(c0 + r) * D_MODEL + r0 + c] = f2b(tile[c][r]);
  }
}

// ---- pack mask int32 -> bit-words (bit lane = mask!=0), one u64 per 64 keys ----
__global__ __launch_bounds__(256) void maskpack_kernel(
    const int* __restrict__ mask, unsigned long long* __restrict__ mbits) {
  size_t gw = ((size_t)blockIdx.x * 256 + threadIdx.x) >> 6;
  int lane = threadIdx.x & 63;
  int val = mask[gw * 64 + lane];
  unsigned long long bits = __ballot(val != 0);
  if (lane == 0) mbits[gw] = bits;
}

// ---- fused QKV projection GEMM: 128x128 tile, BK=64, reg-prefetch pipeline,
//      XCD-swizzled so the 24 blocks sharing an A-panel run on one XCD ----
__global__ __launch_bounds__(256) void gemm_qkv_kernel(
    const float* __restrict__ q, const float* __restrict__ k, const float* __restrict__ v,
    const unsigned short* __restrict__ wqt, const unsigned short* __restrict__ wkt,
    const unsigned short* __restrict__ wvt,
    const float* __restrict__ bq, const float* __restrict__ bv,
    unsigned short* __restrict__ qh, unsigned short* __restrict__ kh,
    unsigned short* __restrict__ vt) {
  __shared__ unsigned short As[128 * 72], Bs[128 * 72];
  int bid = blockIdx.x;
  int xcd = bid & 7, s8 = bid >> 3;        // 96 slots per XCD
  int mloc = s8 / 24, rem = s8 % 24;       // 4 m-panels per XCD
  int z = rem >> 3;
  int n0 = (rem & 7) * 128;
  int m0 = (mloc * 8 + xcd) * 128;
  const float* A; const unsigned short* Bt;
  switch (z) {
    case 0:  A = q; Bt = wqt; break;
    case 1:  A = k; Bt = wkt; break;
    default: A = v; Bt = wvt; break;
  }
  int t = threadIdx.x, lane = t & 63, wave = t >> 6;
  int l16 = lane & 15, quad = lane >> 4;
  int wm = (wave & 1) * 64, wn = (wave >> 1) * 64;
  f32x4 zero = {0.f, 0.f, 0.f, 0.f};
  f32x4 acc[4][4];
  for (int mt = 0; mt < 4; ++mt) for (int nt = 0; nt < 4; ++nt) acc[mt][nt] = zero;

  int sr = t >> 1, sc = (t & 1) * 32;
  const float* aptr = A + (size_t)(m0 + sr) * D_MODEL + sc;
  const unsigned short* bptr = Bt + (size_t)(n0 + sr) * D_MODEL + sc;

  float4 pa[8]; int4 pbv[4];
  auto qkv_load = [&](int k0) {
#pragma unroll
    for (int j = 0; j < 4; ++j) {
      pa[2 * j]     = *(const float4*)(aptr + k0 + j * 8);
      pa[2 * j + 1] = *(const float4*)(aptr + k0 + j * 8 + 4);
      pbv[j]        = *(const int4*)(bptr + k0 + j * 8);
    }
  };

  qkv_load(0);
  for (int k0 = 0; k0 < D_MODEL; k0 += 64) {
    __syncthreads();
#pragma unroll
    for (int j = 0; j < 4; ++j) {
      int4 w;
      w.x = pk2(pa[2 * j].x, pa[2 * j].y);
      w.y = pk2(pa[2 * j].z, pa[2 * j].w);
      w.z = pk2(pa[2 * j + 1].x, pa[2 * j + 1].y);
      w.w = pk2(pa[2 * j + 1].z, pa[2 * j + 1].w);
      *(int4*)&As[sr * 72 + sc + j * 8] = w;
      *(int4*)&Bs[sr * 72 + sc + j * 8] = pbv[j];
    }
    __syncthreads();
    if (k0 + 64 < D_MODEL) qkv_load(k0 + 64);   // prefetch next chunk
#pragma unroll
    for (int half = 0; half < 2; ++half) {
      bf16x8 a[4], b[4];
      for (int mt = 0; mt < 4; ++mt)
        a[mt] = *(const bf16x8*)&As[(wm + mt * 16 + l16) * 72 + half * 32 + quad * 8];
      for (int nt = 0; nt < 4; ++nt)
        b[nt] = *(const bf16x8*)&Bs[(wn + nt * 16 + l16) * 72 + half * 32 + quad * 8];
      for (int mt = 0; mt < 4; ++mt)
        for (int nt = 0; nt < 4; ++nt)
          acc[mt][nt] = __builtin_amdgcn_mfma_f32_16x16x32_bf16(a[mt], b[nt], acc[mt][nt], 0, 0, 0);
    }
  }

  if (z == 2) {
    for (int nt = 0; nt < 4; ++nt) {
      int col = n0 + wn + nt * 16 + l16;
      float bb = bv[col];
      int h = col >> 6, d = col & 63;
      for (int mt = 0; mt < 4; ++mt)
        for (int r = 0; r < 4; ++r) {
          int row = m0 + wm + mt * 16 + quad * 4 + r;
          int b_ = row >> 11, s = row & (SEQ - 1);
          vt[(((size_t)(b_ * NHEAD + h) * DK) + d) * SEQ + s] = f2b_rhu(acc[mt][nt][r] + bb);
        }
    }
  } else if (z == 0) {
    // Q path: fold log2(e)/temperature into the projection output
    for (int nt = 0; nt < 4; ++nt) {
      int col = n0 + wn + nt * 16 + l16;
      float bb = bq[col];
      int h = col >> 6, d = col & 63;
      for (int mt = 0; mt < 4; ++mt)
        for (int r = 0; r < 4; ++r) {
          int row = m0 + wm + mt * 16 + quad * 4 + r;
          int b_ = row >> 11, s = row & (SEQ - 1);
          qh[(((size_t)(b_ * NHEAD + h) * SEQ) + s) * DK + d] =
              f2b_rhu((acc[mt][nt][r] + bb) * QSCALE);
        }
    }
  } else {
    for (int nt = 0; nt < 4; ++nt) {
      int col = n0 + wn + nt * 16 + l16;
      int h = col >> 6, d = col & 63;
      for (int mt = 0; mt < 4; ++mt)
        for (int r = 0; r < 4; ++r) {
          int row = m0 + wm + mt * 16 + quad * 4 + r;
          int b_ = row >> 11, s = row & (SEQ - 1);
          kh[(((size_t)(b_ * NHEAD + h) * SEQ) + s) * DK + d] = f2b_rhu(acc[mt][nt][r]);
        }
    }
  }
}

// ---- output projection GEMM: 64x64 tiles, reg-prefetch, XCD swizzle ----
__global__ __launch_bounds__(256) void gemm_out_kernel(
    const unsigned short* __restrict__ A, const unsigned short* __restrict__ Bt,
    const float* __restrict__ bias, float* __restrict__ out) {
  __shared__ unsigned short As[64 * 72], Bs[64 * 72];
  int bid = blockIdx.x;
  int xcd = bid & 7, s8 = bid >> 3;        // 128 slots per XCD
  int mloc = s8 >> 4, rem = s8 & 15;       // 8 m-panels per XCD, n innermost
  int m0 = (mloc * 8 + xcd) * 64, n0 = rem * 64;
  int t = threadIdx.x, lane = t & 63, wave = t >> 6;
  int l16 = lane & 15, quad = lane >> 4;
  int wm = (wave & 1) * 32, wn = (wave >> 1) * 32;
  f32x4 zero = {0.f, 0.f, 0.f, 0.f};
  f32x4 acc[2][2];
  for (int mt = 0; mt < 2; ++mt) for (int nt = 0; nt < 2; ++nt) acc[mt][nt] = zero;

  int sr = t >> 2, sc = (t & 3) * 8;
  const unsigned short* aptr = A + (size_t)(m0 + sr) * D_MODEL + sc;
  const unsigned short* bptr = Bt + (size_t)(n0 + sr) * D_MODEL + sc;

  int4 pa2[2], pb2[2];
  auto gout_load = [&](int k0) {
    pa2[0] = *(const int4*)(aptr + k0);
    pa2[1] = *(const int4*)(aptr + k0 + 32);
    pb2[0] = *(const int4*)(bptr + k0);
    pb2[1] = *(const int4*)(bptr + k0 + 32);
  };

  gout_load(0);
  for (int k0 = 0; k0 < D_MODEL; k0 += 64) {
    __syncthreads();
    *(int4*)&As[sr * 72 + sc]      = pa2[0];
    *(int4*)&As[sr * 72 + sc + 32] = pa2[1];
    *(int4*)&Bs[sr * 72 + sc]      = pb2[0];
    *(int4*)&Bs[sr * 72 + sc + 32] = pb2[1];
    __syncthreads();
    if (k0 + 64 < D_MODEL) gout_load(k0 + 64);
#pragma unroll
    for (int half = 0; half < 2; ++half) {
      bf16x8 a[2], b[2];
      for (int mt = 0; mt < 2; ++mt)
        a[mt] = *(const bf16x8*)&As[(wm + mt * 16 + l16) * 72 + half * 32 + quad * 8];
      for (int nt = 0; nt < 2; ++nt)
        b[nt] = *(const bf16x8*)&Bs[(wn + nt * 16 + l16) * 72 + half * 32 + quad * 8];
      for (int mt = 0; mt < 2; ++mt)
        for (int nt = 0; nt < 2; ++nt)
          acc[mt][nt] = __builtin_amdgcn_mfma_f32_16x16x32_bf16(a[mt], b[nt], acc[mt][nt], 0, 0, 0);
    }
  }
  for (int nt = 0; nt < 2; ++nt) {
    int col = n0 + wn + nt * 16 + l16;
    float bb = bias[col];
    for (int mt = 0; mt < 2; ++mt)
      for (int r = 0; r < 4; ++r) {
        int row = m0 + wm + mt * 16 + quad * 4 + r;
        out[(size_t)row * D_MODEL + col] = acc[mt][nt][r] + bb;
      }
  }
}

// ---- flash attention. Q pre-scaled by log2(e)/8 => p = exp2(s) directly.
// Mask applied as sign-extended AND on packed bf16. Row-sums via MFMA with a
// ones B-fragment (no per-element adds, no final shuffle reduce).
// P buffer aliases the dead Qs region (Q frags hoisted to registers). ----
__global__ __launch_bounds__(256) void attn_kernel(
    const unsigned short* __restrict__ qh, const unsigned short* __restrict__ kh,
    const unsigned short* __restrict__ vt, const unsigned long long* __restrict__ mbits,
    unsigned short* __restrict__ attb) {
  __shared__ unsigned short Qs[64 * 72], Ks[64 * 72], Vs[64 * 72];  // 27.6 KB
  int bid = blockIdx.x;
  int xcd = bid & 7, s8 = bid >> 3;          // 128 slots/xcd
  int bh_ = 4 * xcd + (s8 >> 5);             // 4 (b,h) pairs per XCD
  int qt = s8 & 31;
  int b = bh_ >> 4, h = bh_ & 15;
  int t = threadIdx.x, lane = t & 63, wave = t >> 6;
  int l16 = lane & 15, quad = lane >> 4;
  size_t bh = (size_t)b * NHEAD + h;

  int sr = t >> 2, sc = (t & 3) * 8;
  // stage Q tile, hoist Q A-fragments to registers, then reuse Qs for P
  const unsigned short* Qg = qh + (bh * SEQ + (size_t)qt * 64) * DK;
  *(int4*)&Qs[sr * 72 + sc]      = *(const int4*)&Qg[sr * DK + sc];
  *(int4*)&Qs[sr * 72 + sc + 32] = *(const int4*)&Qg[sr * DK + sc + 32];
  __syncthreads();
  bf16x8 qf[2];
  qf[0] = *(const bf16x8*)&Qs[(wave * 16 + l16) * 72 + quad * 8];
  qf[1] = *(const bf16x8*)&Qs[(wave * 16 + l16) * 72 + 32 + quad * 8];
  unsigned short* Pw = &Qs[wave * 16 * 68];   // wave-private, stride 68

  const unsigned short* Kg = kh + bh * SEQ * DK;
  const unsigned short* Vg = vt + bh * DK * SEQ;
  const unsigned long long* mrow = mbits + (size_t)b * SEQ * (SEQ / 64);
  int qrow0 = qt * 64 + wave * 16 + quad * 4;

  bf16x8 ones;
#pragma unroll
  for (int i = 0; i < 8; ++i) ones[i] = (short)0x3F80;  // bf16 1.0

  f32x4 zero = {0.f, 0.f, 0.f, 0.f};
  f32x4 accO[4], accRS = zero;
  for (int nt = 0; nt < 4; ++nt) accO[nt] = zero;

  int4 kreg[2], vreg[2];
  auto attn_load = [&](int tk) {
    const unsigned short* Kt = Kg + (size_t)tk * 64 * DK;
    kreg[0] = *(const int4*)&Kt[sr * DK + sc];
    kreg[1] = *(const int4*)&Kt[sr * DK + sc + 32];
    const unsigned short* Vt_ = Vg + (size_t)tk * 64;
    vreg[0] = *(const int4*)&Vt_[(size_t)sr * SEQ + sc];
    vreg[1] = *(const int4*)&Vt_[(size_t)sr * SEQ + sc + 32];
  };

  attn_load(0);
  for (int tk = 0; tk < SEQ / 64; ++tk) {
    __syncthreads();
    *(int4*)&Ks[sr * 72 + sc]      = kreg[0];
    *(int4*)&Ks[sr * 72 + sc + 32] = kreg[1];
    *(int4*)&Vs[sr * 72 + sc]      = vreg[0];
    *(int4*)&Vs[sr * 72 + sc + 32] = vreg[1];
    __syncthreads();
    if (tk + 1 < SEQ / 64) attn_load(tk + 1);   // prefetch next K/V tile

    unsigned long long mw[4];
#pragma unroll
    for (int r = 0; r < 4; ++r)
      mw[r] = mrow[(size_t)(qrow0 + r) * (SEQ / 64) + tk] >> l16;

    // S = Q K^T (pre-scaled)
    f32x4 accS[4];
    for (int nt = 0; nt < 4; ++nt) accS[nt] = zero;
#pragma unroll
    for (int step = 0; step < 2; ++step)
      for (int nt = 0; nt < 4; ++nt) {
        bf16x8 bk = *(const bf16x8*)&Ks[(nt * 16 + l16) * 72 + step * 32 + quad * 8];
        accS[nt] = __builtin_amdgcn_mfma_f32_16x16x32_bf16(qf[step], bk, accS[nt], 0, 0, 0);
      }

    // p = exp2(s), mask via sign-extended AND on the packed bf16
#pragma unroll
    for (int r = 0; r < 4; ++r) {
      unsigned lo = (unsigned)mw[r], hi = (unsigned)(mw[r] >> 32);
#pragma unroll
      for (int nt = 0; nt < 4; ++nt) {
        unsigned halfw = (nt < 2) ? lo : hi;
        const int sh = 31 - ((nt & 1) * 16);
        float pv = __builtin_amdgcn_exp2f(accS[nt][r]);
        unsigned u = (__builtin_bit_cast(unsigned, pv) + 0x8000u) >> 16;
        int mskv = ((int)(halfw << sh)) >> 31;          // 0 or -1
        Pw[(quad * 4 + r) * 68 + nt * 16 + l16] = (unsigned short)(u & (unsigned)mskv);
      }
    }

    // O += P V ; row-sums += P * ones
#pragma unroll
    for (int step = 0; step < 2; ++step) {
      short4 plo = *(const short4*)&Pw[l16 * 68 + step * 32 + quad * 8];
      short4 phi = *(const short4*)&Pw[l16 * 68 + step * 32 + quad * 8 + 4];
      bf16x8 ap = {plo.x, plo.y, plo.z, plo.w, phi.x, phi.y, phi.z, phi.w};
      accRS = __builtin_amdgcn_mfma_f32_16x16x32_bf16(ap, ones, accRS, 0, 0, 0);
      for (int nt = 0; nt < 4; ++nt) {
        bf16x8 bv_ = *(const bf16x8*)&Vs[(nt * 16 + l16) * 72 + step * 32 + quad * 8];
        accO[nt] = __builtin_amdgcn_mfma_f32_16x16x32_bf16(ap, bv_, accO[nt], 0, 0, 0);
      }
    }
  }

  // epilogue: normalize by MFMA row-sums, write [b][s][h*64+d] bf16
  for (int r = 0; r < 4; ++r) {
    float sden = accRS[r];
    float inv = sden > 0.f ? 1.f / sden : 0.f;
    int row = qt * 64 + wave * 16 + quad * 4 + r;
    size_t ob = ((size_t)b * SEQ + row) * D_MODEL + (size_t)h * DK;
    for (int nt = 0; nt < 4; ++nt)
      attb[ob + nt * 16 + l16] = f2b_rhu(accO[nt][r] * inv);
  }
}

extern "C" void kernel_launch(void* const* d_in, const int* in_sizes, int n_in,
                              void* d_out, int out_size, void* d_ws, size_t ws_size,
                              hipStream_t stream) {
  (void)in_sizes; (void)n_in; (void)out_size; (void)ws_size;
  const float* q    = (const float*)d_in[0];
  const float* k    = (const float*)d_in[1];
  const float* v    = (const float*)d_in[2];
  const int*   mask = (const int*)d_in[3];
  const float* wq   = (const float*)d_in[4];
  const float* bq   = (const float*)d_in[5];
  const float* wk   = (const float*)d_in[6];
  const float* wv   = (const float*)d_in[7];
  const float* bv   = (const float*)d_in[8];
  const float* wf   = (const float*)d_in[9];
  const float* bf   = (const float*)d_in[10];

  char* ws = (char*)d_ws;
  // workspace layout (bytes) -- total ~36.7 MiB (round-0's 73 MiB overflowed
  // d_ws and corrupted harness pristine buffers; 36.7 MiB is proven safe).
  // wqt/wkt/wvt dead after gemm_qkv; attb aliases them.
  unsigned short* wft  = (unsigned short*)(ws + 0);          // 2 MiB, live till end
  unsigned short* wqt  = (unsigned short*)(ws + 2097152);    // 2 MiB
  unsigned short* wkt  = (unsigned short*)(ws + 4194304);    // 2 MiB
  unsigned short* wvt  = (unsigned short*)(ws + 6291456);    // 2 MiB
  unsigned short* attb = (unsigned short*)(ws + 2097152);    // 8 MiB alias
  unsigned short* qhp  = (unsigned short*)(ws + 10485760);   // 8 MiB
  unsigned short* khp  = (unsigned short*)(ws + 18874368);   // 8 MiB
  unsigned short* vtp  = (unsigned short*)(ws + 27262976);   // 8 MiB
  unsigned long long* mbits = (unsigned long long*)(ws + 35651584); // 1 MiB

  hipLaunchKernelGGL(wtrans_kernel, dim3(16, 16, 4), dim3(256), 0, stream,
                     wq, wk, wv, wf, wqt, wkt, wvt, wft);
  hipLaunchKernelGGL(maskpack_kernel, dim3(32768), dim3(256), 0, stream, mask, mbits);
  hipLaunchKernelGGL(gemm_qkv_kernel, dim3(768), dim3(256), 0, stream,
                     q, k, v, wqt, wkt, wvt, bq, bv, qhp, khp, vtp);
  hipLaunchKernelGGL(attn_kernel, dim3(1024), dim3(256), 0, stream,
                     qhp, khp, vtp, mbits, attb);
  hipLaunchKernelGGL(gemm_out_kernel, dim3(1024), dim3(256), 0, stream,
                     attb, wft, bf, (float*)d_out);
}

// Round 6
// 328.018 us; speedup vs baseline: 1.5039x; 1.5039x over previous
//
#include <hip/hip_runtime.h>

// ---- problem constants ----
#define D_MODEL 1024
#define NHEAD   16
#define DK      64
#define BATCH   2
#define SEQ     2048

typedef __attribute__((ext_vector_type(8))) short bf16x8;
typedef __attribute__((ext_vector_type(4))) float f32x4;

#define QSCALE 0.18033688011f   // log2(e) / sqrt(64): folded into Q projection

__device__ __forceinline__ unsigned short f2b(float x) {
  unsigned u = __builtin_bit_cast(unsigned, x);
  u = (u + 0x7fffu + ((u >> 16) & 1u)) >> 16;   // RNE to bf16
  return (unsigned short)u;
}
// round-half-up bf16 (bias 2^-17 rel, error <= 2^-9 like RNE) -- 1 add
__device__ __forceinline__ unsigned short f2b_rhu(float x) {
  return (unsigned short)((__builtin_bit_cast(unsigned, x) + 0x8000u) >> 16);
}
// pack two fp32 -> two bf16 (round-half-up) in 3 VALU: add, add, v_perm
__device__ __forceinline__ int pk2(float a, float b) {
  unsigned ua = __builtin_bit_cast(unsigned, a) + 0x8000u;
  unsigned ub = __builtin_bit_cast(unsigned, b) + 0x8000u;
  return (int)__builtin_amdgcn_perm(ub, ua, 0x07060302u);  // [ub.hi16 : ua.hi16]
}

// ---- transpose + cast weights: w[in][out] fp32 -> wt[out][in] bf16 ----
__global__ __launch_bounds__(256) void wtrans_kernel(
    const float* __restrict__ wq, const float* __restrict__ wk,
    const float* __restrict__ wv, const float* __restrict__ wf,
    unsigned short* __restrict__ wqt, unsigned short* __restrict__ wkt,
    unsigned short* __restrict__ wvt, unsigned short* __restrict__ wft) {
  __shared__ float tile[64][65];
  const float* w; unsigned short* wt;
  switch (blockIdx.z) {
    case 0: w = wq; wt = wqt; break;
    case 1: w = wk; wt = wkt; break;
    case 2: w = wv; wt = wvt; break;
    default: w = wf; wt = wft; break;
  }
  int r0 = blockIdx.y * 64, c0 = blockIdx.x * 64;
  int t = threadIdx.x;
  for (int i = 0; i < 16; ++i) {
    int idx = t + i * 256; int r = idx >> 6, c = idx & 63;
    tile[r][c] = w[(size_t)(r0 + r) * D_MODEL + c0 + c];
  }
  __syncthreads();
  for (int i = 0; i < 16; ++i) {
    int idx = t + i * 256; int r = idx >> 6, c = idx & 63;
    wt[(size_t)(c0 + r) * D_MODEL + r0 + c] = f2b(tile[c][r]);
  }
}

// ---- pack mask int32 -> bit-words (bit lane = mask!=0), one u64 per 64 keys ----
__global__ __launch_bounds__(256) void maskpack_kernel(
    const int* __restrict__ mask, unsigned long long* __restrict__ mbits) {
  size_t gw = ((size_t)blockIdx.x * 256 + threadIdx.x) >> 6;
  int lane = threadIdx.x & 63;
  int val = mask[gw * 64 + lane];
  unsigned long long bits = __ballot(val != 0);
  if (lane == 0) mbits[gw] = bits;
}

// ---- fused QKV projection GEMM: 128x128 tile, BK=64 (R4-proven body).
// XCD-sticky mapping: each XCD owns 4 A-panels (2 MB fp32, L2-resident),
// zn walks outer so A is fetched ~once per XCD. No register prefetch
// (R5's prefetch lambdas spilled to scratch: WRITE_SIZE 8->236 MB). ----
__global__ __launch_bounds__(256) void gemm_qkv_kernel(
    const float* __restrict__ q, const float* __restrict__ k, const float* __restrict__ v,
    const unsigned short* __restrict__ wqt, const unsigned short* __restrict__ wkt,
    const unsigned short* __restrict__ wvt,
    const float* __restrict__ bq, const float* __restrict__ bv,
    unsigned short* __restrict__ qh, unsigned short* __restrict__ kh,
    unsigned short* __restrict__ vt) {
  __shared__ unsigned short As[128 * 72], Bs[128 * 72];
  int bid = blockIdx.x;
  int xcd = bid & 7, slot = bid >> 3;      // 96 slots per XCD
  int mi = slot & 3, zn = slot >> 2;       // 4 m-panels per XCD, zn in [0,24)
  int z = zn >> 3;
  int n0 = (zn & 7) * 128;
  int m0 = (mi * 8 + xcd) * 128;
  const float* A; const unsigned short* Bt;
  switch (z) {
    case 0:  A = q; Bt = wqt; break;
    case 1:  A = k; Bt = wkt; break;
    default: A = v; Bt = wvt; break;
  }
  int t = threadIdx.x, lane = t & 63, wave = t >> 6;
  int l16 = lane & 15, quad = lane >> 4;
  int wm = (wave & 1) * 64, wn = (wave >> 1) * 64;
  f32x4 zero = {0.f, 0.f, 0.f, 0.f};
  f32x4 acc[4][4];
  for (int mt = 0; mt < 4; ++mt) for (int nt = 0; nt < 4; ++nt) acc[mt][nt] = zero;

  int sr = t >> 1, sc = (t & 1) * 32;
  const float* aptr = A + (size_t)(m0 + sr) * D_MODEL + sc;
  const unsigned short* bptr = Bt + (size_t)(n0 + sr) * D_MODEL + sc;

  for (int k0 = 0; k0 < D_MODEL; k0 += 64) {
    __syncthreads();
#pragma unroll
    for (int j = 0; j < 4; ++j) {
      float4 x0 = *(const float4*)(aptr + k0 + j * 8);
      float4 x1 = *(const float4*)(aptr + k0 + j * 8 + 4);
      int4 w;
      w.x = pk2(x0.x, x0.y); w.y = pk2(x0.z, x0.w);
      w.z = pk2(x1.x, x1.y); w.w = pk2(x1.z, x1.w);
      *(int4*)&As[sr * 72 + sc + j * 8] = w;
      *(int4*)&Bs[sr * 72 + sc + j * 8] = *(const int4*)(bptr + k0 + j * 8);
    }
    __syncthreads();
#pragma unroll
    for (int half = 0; half < 2; ++half) {
      bf16x8 a[4], b[4];
      for (int mt = 0; mt < 4; ++mt)
        a[mt] = *(const bf16x8*)&As[(wm + mt * 16 + l16) * 72 + half * 32 + quad * 8];
      for (int nt = 0; nt < 4; ++nt)
        b[nt] = *(const bf16x8*)&Bs[(wn + nt * 16 + l16) * 72 + half * 32 + quad * 8];
      for (int mt = 0; mt < 4; ++mt)
        for (int nt = 0; nt < 4; ++nt)
          acc[mt][nt] = __builtin_amdgcn_mfma_f32_16x16x32_bf16(a[mt], b[nt], acc[mt][nt], 0, 0, 0);
    }
  }

  if (z == 2) {
    for (int nt = 0; nt < 4; ++nt) {
      int col = n0 + wn + nt * 16 + l16;
      float bb = bv[col];
      int h = col >> 6, d = col & 63;
      for (int mt = 0; mt < 4; ++mt)
        for (int r = 0; r < 4; ++r) {
          int row = m0 + wm + mt * 16 + quad * 4 + r;
          int b_ = row >> 11, s = row & (SEQ - 1);
          vt[(((size_t)(b_ * NHEAD + h) * DK) + d) * SEQ + s] = f2b_rhu(acc[mt][nt][r] + bb);
        }
    }
  } else if (z == 0) {
    // Q path: fold log2(e)/temperature into the projection output
    for (int nt = 0; nt < 4; ++nt) {
      int col = n0 + wn + nt * 16 + l16;
      float bb = bq[col];
      int h = col >> 6, d = col & 63;
      for (int mt = 0; mt < 4; ++mt)
        for (int r = 0; r < 4; ++r) {
          int row = m0 + wm + mt * 16 + quad * 4 + r;
          int b_ = row >> 11, s = row & (SEQ - 1);
          qh[(((size_t)(b_ * NHEAD + h) * SEQ) + s) * DK + d] =
              f2b_rhu((acc[mt][nt][r] + bb) * QSCALE);
        }
    }
  } else {
    for (int nt = 0; nt < 4; ++nt) {
      int col = n0 + wn + nt * 16 + l16;
      int h = col >> 6, d = col & 63;
      for (int mt = 0; mt < 4; ++mt)
        for (int r = 0; r < 4; ++r) {
          int row = m0 + wm + mt * 16 + quad * 4 + r;
          int b_ = row >> 11, s = row & (SEQ - 1);
          kh[(((size_t)(b_ * NHEAD + h) * SEQ) + s) * DK + d] = f2b_rhu(acc[mt][nt][r]);
        }
    }
  }
}

// ---- output projection GEMM: 64x64 tiles (R4 body), XCD-sticky m-panels ----
__global__ __launch_bounds__(256) void gemm_out_kernel(
    const unsigned short* __restrict__ A, const unsigned short* __restrict__ Bt,
    const float* __restrict__ bias, float* __restrict__ out) {
  __shared__ unsigned short As[64 * 72], Bs[64 * 72];
  int bid = blockIdx.x;
  int xcd = bid & 7, slot = bid >> 3;      // 128 slots per XCD
  int mi = slot & 7, n0 = (slot >> 3) * 64;
  int m0 = (mi * 8 + xcd) * 64;
  int t = threadIdx.x, lane = t & 63, wave = t >> 6;
  int l16 = lane & 15, quad = lane >> 4;
  int wm = (wave & 1) * 32, wn = (wave >> 1) * 32;
  f32x4 zero = {0.f, 0.f, 0.f, 0.f};
  f32x4 acc[2][2];
  for (int mt = 0; mt < 2; ++mt) for (int nt = 0; nt < 2; ++nt) acc[mt][nt] = zero;

  int sr = t >> 2, sc = (t & 3) * 8;
  const unsigned short* aptr = A + (size_t)(m0 + sr) * D_MODEL + sc;
  const unsigned short* bptr = Bt + (size_t)(n0 + sr) * D_MODEL + sc;

  for (int k0 = 0; k0 < D_MODEL; k0 += 64) {
    __syncthreads();
    *(int4*)&As[sr * 72 + sc]      = *(const int4*)(aptr + k0);
    *(int4*)&As[sr * 72 + sc + 32] = *(const int4*)(aptr + k0 + 32);
    *(int4*)&Bs[sr * 72 + sc]      = *(const int4*)(bptr + k0);
    *(int4*)&Bs[sr * 72 + sc + 32] = *(const int4*)(bptr + k0 + 32);
    __syncthreads();
#pragma unroll
    for (int half = 0; half < 2; ++half) {
      bf16x8 a[2], b[2];
      for (int mt = 0; mt < 2; ++mt)
        a[mt] = *(const bf16x8*)&As[(wm + mt * 16 + l16) * 72 + half * 32 + quad * 8];
      for (int nt = 0; nt < 2; ++nt)
        b[nt] = *(const bf16x8*)&Bs[(wn + nt * 16 + l16) * 72 + half * 32 + quad * 8];
      for (int mt = 0; mt < 2; ++mt)
        for (int nt = 0; nt < 2; ++nt)
          acc[mt][nt] = __builtin_amdgcn_mfma_f32_16x16x32_bf16(a[mt], b[nt], acc[mt][nt], 0, 0, 0);
    }
  }
  for (int nt = 0; nt < 2; ++nt) {
    int col = n0 + wn + nt * 16 + l16;
    float bb = bias[col];
    for (int mt = 0; mt < 2; ++mt)
      for (int r = 0; r < 4; ++r) {
        int row = m0 + wm + mt * 16 + quad * 4 + r;
        out[(size_t)row * D_MODEL + col] = acc[mt][nt][r] + bb;
      }
  }
}

// ---- flash attention (R4 staging body, no register prefetch).
// Q pre-scaled => p = exp2(s) directly. Mask = sign-extend AND on packed
// bf16. Row-sums via MFMA with a ones B-fragment. XCD-sticky (b,h): the 32
// qt-blocks sharing one KV set (512 KB) run on one XCD -> KV stays in L2. ----
__global__ __launch_bounds__(256) void attn_kernel(
    const unsigned short* __restrict__ qh, const unsigned short* __restrict__ kh,
    const unsigned short* __restrict__ vt, const unsigned long long* __restrict__ mbits,
    unsigned short* __restrict__ attb) {
  __shared__ unsigned short Qs[64 * 72], Ks[64 * 72], Vs[64 * 72];
  __shared__ unsigned short Ps[4][16 * 68];
  int bid = blockIdx.x;
  int xcd = bid & 7, slot = bid >> 3;        // 128 slots per XCD
  int bh_ = 4 * xcd + (slot >> 5);           // 4 (b,h) pairs per XCD
  int qt = slot & 31;
  int b = bh_ >> 4, h = bh_ & 15;
  int t = threadIdx.x, lane = t & 63, wave = t >> 6;
  int l16 = lane & 15, quad = lane >> 4;
  size_t bh = (size_t)b * NHEAD + h;

  int sr = t >> 2, sc = (t & 3) * 8;
  // stage Q tile, hoist Q A-fragments to registers
  const unsigned short* Qg = qh + (bh * SEQ + (size_t)qt * 64) * DK;
  *(int4*)&Qs[sr * 72 + sc]      = *(const int4*)&Qg[sr * DK + sc];
  *(int4*)&Qs[sr * 72 + sc + 32] = *(const int4*)&Qg[sr * DK + sc + 32];
  __syncthreads();
  bf16x8 qf[2];
  qf[0] = *(const bf16x8*)&Qs[(wave * 16 + l16) * 72 + quad * 8];
  qf[1] = *(const bf16x8*)&Qs[(wave * 16 + l16) * 72 + 32 + quad * 8];
  unsigned short* Pw = Ps[wave];

  const unsigned short* Kg = kh + bh * SEQ * DK;
  const unsigned short* Vg = vt + bh * DK * SEQ;
  const unsigned long long* mrow = mbits + (size_t)b * SEQ * (SEQ / 64);
  int qrow0 = qt * 64 + wave * 16 + quad * 4;

  bf16x8 ones;
#pragma unroll
  for (int i = 0; i < 8; ++i) ones[i] = (short)0x3F80;  // bf16 1.0

  f32x4 zero = {0.f, 0.f, 0.f, 0.f};
  f32x4 accO[4], accRS = zero;
  for (int nt = 0; nt < 4; ++nt) accO[nt] = zero;

  for (int tk = 0; tk < SEQ / 64; ++tk) {
    __syncthreads();
    {
      const unsigned short* Kt = Kg + (size_t)tk * 64 * DK;
      *(int4*)&Ks[sr * 72 + sc]      = *(const int4*)&Kt[sr * DK + sc];
      *(int4*)&Ks[sr * 72 + sc + 32] = *(const int4*)&Kt[sr * DK + sc + 32];
      const unsigned short* Vt_ = Vg + (size_t)tk * 64;
      *(int4*)&Vs[sr * 72 + sc]      = *(const int4*)&Vt_[(size_t)sr * SEQ + sc];
      *(int4*)&Vs[sr * 72 + sc + 32] = *(const int4*)&Vt_[(size_t)sr * SEQ + sc + 32];
    }
    __syncthreads();

    unsigned long long mw[4];
#pragma unroll
    for (int r = 0; r < 4; ++r)
      mw[r] = mrow[(size_t)(qrow0 + r) * (SEQ / 64) + tk] >> l16;

    // S = Q K^T (pre-scaled)
    f32x4 accS[4];
    for (int nt = 0; nt < 4; ++nt) accS[nt] = zero;
#pragma unroll
    for (int step = 0; step < 2; ++step)
      for (int nt = 0; nt < 4; ++nt) {
        bf16x8 bk = *(const bf16x8*)&Ks[(nt * 16 + l16) * 72 + step * 32 + quad * 8];
        accS[nt] = __builtin_amdgcn_mfma_f32_16x16x32_bf16(qf[step], bk, accS[nt], 0, 0, 0);
      }

    // p = exp2(s), mask via sign-extended AND on the packed bf16
#pragma unroll
    for (int r = 0; r < 4; ++r) {
      unsigned lo = (unsigned)mw[r], hi = (unsigned)(mw[r] >> 32);
#pragma unroll
      for (int nt = 0; nt < 4; ++nt) {
        unsigned halfw = (nt < 2) ? lo : hi;
        const int sh = 31 - ((nt & 1) * 16);
        float pv = __builtin_amdgcn_exp2f(accS[nt][r]);
        unsigned u = (__builtin_bit_cast(unsigned, pv) + 0x8000u) >> 16;
        int mskv = ((int)(halfw << sh)) >> 31;          // 0 or -1
        Pw[(quad * 4 + r) * 68 + nt * 16 + l16] = (unsigned short)(u & (unsigned)mskv);
      }
    }

    // O += P V ; row-sums += P * ones
#pragma unroll
    for (int step = 0; step < 2; ++step) {
      short4 plo = *(const short4*)&Pw[l16 * 68 + step * 32 + quad * 8];
      short4 phi = *(const short4*)&Pw[l16 * 68 + step * 32 + quad * 8 + 4];
      bf16x8 ap = {plo.x, plo.y, plo.z, plo.w, phi.x, phi.y, phi.z, phi.w};
      accRS = __builtin_amdgcn_mfma_f32_16x16x32_bf16(ap, ones, accRS, 0, 0, 0);
      for (int nt = 0; nt < 4; ++nt) {
        bf16x8 bv_ = *(const bf16x8*)&Vs[(nt * 16 + l16) * 72 + step * 32 + quad * 8];
        accO[nt] = __builtin_amdgcn_mfma_f32_16x16x32_bf16(ap, bv_, accO[nt], 0, 0, 0);
      }
    }
  }

  // epilogue: normalize by MFMA row-sums, write [b][s][h*64+d] bf16
  for (int r = 0; r < 4; ++r) {
    float sden = accRS[r];
    float inv = sden > 0.f ? 1.f / sden : 0.f;
    int row = qt * 64 + wave * 16 + quad * 4 + r;
    size_t ob = ((size_t)b * SEQ + row) * D_MODEL + (size_t)h * DK;
    for (int nt = 0; nt < 4; ++nt)
      attb[ob + nt * 16 + l16] = f2b_rhu(accO[nt][r] * inv);
  }
}

extern "C" void kernel_launch(void* const* d_in, const int* in_sizes, int n_in,
                              void* d_out, int out_size, void* d_ws, size_t ws_size,
                              hipStream_t stream) {
  (void)in_sizes; (void)n_in; (void)out_size; (void)ws_size;
  const float* q    = (const float*)d_in[0];
  const float* k    = (const float*)d_in[1];
  const float* v    = (const float*)d_in[2];
  const int*   mask = (const int*)d_in[3];
  const float* wq   = (const float*)d_in[4];
  const float* bq   = (const float*)d_in[5];
  const float* wk   = (const float*)d_in[6];
  const float* wv   = (const float*)d_in[7];
  const float* bv   = (const float*)d_in[8];
  const float* wf   = (const float*)d_in[9];
  const float* bf   = (const float*)d_in[10];

  char* ws = (char*)d_ws;
  // workspace layout (bytes) -- total ~36.7 MiB (proven safe; 73 MiB overflowed
  // in round 0 and corrupted the harness pristine buffers).
  // wqt/wkt/wvt dead after gemm_qkv; attb aliases them.
  unsigned short* wft  = (unsigned short*)(ws + 0);          // 2 MiB, live till end
  unsigned short* wqt  = (unsigned short*)(ws + 2097152);    // 2 MiB
  unsigned short* wkt  = (unsigned short*)(ws + 4194304);    // 2 MiB
  unsigned short* wvt  = (unsigned short*)(ws + 6291456);    // 2 MiB
  unsigned short* attb = (unsigned short*)(ws + 2097152);    // 8 MiB alias
  unsigned short* qhp  = (unsigned short*)(ws + 10485760);   // 8 MiB
  unsigned short* khp  = (unsigned short*)(ws + 18874368);   // 8 MiB
  unsigned short* vtp  = (unsigned short*)(ws + 27262976);   // 8 MiB
  unsigned long long* mbits = (unsigned long long*)(ws + 35651584); // 1 MiB

  hipLaunchKernelGGL(wtrans_kernel, dim3(16, 16, 4), dim3(256), 0, stream,
                     wq, wk, wv, wf, wqt, wkt, wvt, wft);
  hipLaunchKernelGGL(maskpack_kernel, dim3(32768), dim3(256), 0, stream, mask, mbits);
  hipLaunchKernelGGL(gemm_qkv_kernel, dim3(768), dim3(256), 0, stream,
                     q, k, v, wqt, wkt, wvt, bq, bv, qhp, khp, vtp);
  hipLaunchKernelGGL(attn_kernel, dim3(1024), dim3(256), 0, stream,
                     qhp, khp, vtp, mbits, attb);
  hipLaunchKernelGGL(gemm_out_kernel, dim3(1024), dim3(256), 0, stream,
                     attb, wft, bf, (float*)d_out);
}

// Round 7
// 321.867 us; speedup vs baseline: 1.5326x; 1.0191x over previous
//
#include <hip/hip_runtime.h>

// ---- problem constants ----
#define D_MODEL 1024
#define NHEAD   16
#define DK      64
#define BATCH   2
#define SEQ     2048

typedef __attribute__((ext_vector_type(8))) short bf16x8;
typedef __attribute__((ext_vector_type(4))) float f32x4;

#define QSCALE 0.18033688011f   // log2(e) / sqrt(64): folded into Q projection

__device__ __forceinline__ unsigned short f2b(float x) {
  unsigned u = __builtin_bit_cast(unsigned, x);
  u = (u + 0x7fffu + ((u >> 16) & 1u)) >> 16;   // RNE to bf16
  return (unsigned short)u;
}
// round-half-up bf16 (bias 2^-17 rel, error <= 2^-9 like RNE) -- 1 add
__device__ __forceinline__ unsigned short f2b_rhu(float x) {
  return (unsigned short)((__builtin_bit_cast(unsigned, x) + 0x8000u) >> 16);
}
// pack two fp32 -> two bf16 (round-half-up) in 3 VALU: add, add, v_perm
__device__ __forceinline__ int pk2(float a, float b) {
  unsigned ua = __builtin_bit_cast(unsigned, a) + 0x8000u;
  unsigned ub = __builtin_bit_cast(unsigned, b) + 0x8000u;
  return (int)__builtin_amdgcn_perm(ub, ua, 0x07060302u);  // [ub.hi16 : ua.hi16]
}

// async 16B global->LDS (m97 pattern). LDS dest = wave-uniform base + lane*16;
// callers must compute lds ptr in exactly lane order. Drained by __syncthreads.
typedef const __attribute__((address_space(1))) void* gas_p;
typedef __attribute__((address_space(3))) void* las_p;
__device__ __forceinline__ void gll16(const void* g, void* l) {
  __builtin_amdgcn_global_load_lds((gas_p)g, (las_p)l, 16, 0, 0);
}

// ---- transpose + cast weights: w[in][out] fp32 -> wt[out][in] bf16 ----
__global__ __launch_bounds__(256) void wtrans_kernel(
    const float* __restrict__ wq, const float* __restrict__ wk,
    const float* __restrict__ wv, const float* __restrict__ wf,
    unsigned short* __restrict__ wqt, unsigned short* __restrict__ wkt,
    unsigned short* __restrict__ wvt, unsigned short* __restrict__ wft) {
  __shared__ float tile[64][65];
  const float* w; unsigned short* wt;
  switch (blockIdx.z) {
    case 0: w = wq; wt = wqt; break;
    case 1: w = wk; wt = wkt; break;
    case 2: w = wv; wt = wvt; break;
    default: w = wf; wt = wft; break;
  }
  int r0 = blockIdx.y * 64, c0 = blockIdx.x * 64;
  int t = threadIdx.x;
  for (int i = 0; i < 16; ++i) {
    int idx = t + i * 256; int r = idx >> 6, c = idx & 63;
    tile[r][c] = w[(size_t)(r0 + r) * D_MODEL + c0 + c];
  }
  __syncthreads();
  for (int i = 0; i < 16; ++i) {
    int idx = t + i * 256; int r = idx >> 6, c = idx & 63;
    wt[(size_t)(c0 + r) * D_MODEL + r0 + c] = f2b(tile[c][r]);
  }
}

// ---- pack mask int32 -> bit-words (bit lane = mask!=0), one u64 per 64 keys ----
__global__ __launch_bounds__(256) void maskpack_kernel(
    const int* __restrict__ mask, unsigned long long* __restrict__ mbits) {
  size_t gw = ((size_t)blockIdx.x * 256 + threadIdx.x) >> 6;
  int lane = threadIdx.x & 63;
  int val = mask[gw * 64 + lane];
  unsigned long long bits = __ballot(val != 0);
  if (lane == 0) mbits[gw] = bits;
}

// ---- fused QKV projection GEMM: 128x128 tile, BK=64, XCD-sticky mapping.
// B staged via async global_load_lds (unpadded stride 64); A staged explicit
// (fp32->bf16 convert, padded stride 72) overlapping the B DMA.
// V epilogue: LDS-transpose then coalesced 16B stores (was 2B d-major
// scatter -- the R6 straggler tail). ----
__global__ __launch_bounds__(256) void gemm_qkv_kernel(
    const float* __restrict__ q, const float* __restrict__ k, const float* __restrict__ v,
    const unsigned short* __restrict__ wqt, const unsigned short* __restrict__ wkt,
    const unsigned short* __restrict__ wvt,
    const float* __restrict__ bq, const float* __restrict__ bv,
    unsigned short* __restrict__ qh, unsigned short* __restrict__ kh,
    unsigned short* __restrict__ vt) {
  __shared__ unsigned short SB[128 * 72 + 128 * 64];   // As (stride 72) + Bs (stride 64)
  unsigned short* As = SB;
  unsigned short* Bs = SB + 128 * 72;
  int bid = blockIdx.x;
  int xcd = bid & 7, slot = bid >> 3;      // 96 slots per XCD
  int mi = slot & 3, zn = slot >> 2;       // 4 m-panels per XCD, zn in [0,24)
  int z = zn >> 3;
  int n0 = (zn & 7) * 128;
  int m0 = (mi * 8 + xcd) * 128;
  const float* A; const unsigned short* Bt;
  switch (z) {
    case 0:  A = q; Bt = wqt; break;
    case 1:  A = k; Bt = wkt; break;
    default: A = v; Bt = wvt; break;
  }
  int t = threadIdx.x, lane = t & 63, wave = t >> 6;
  int l16 = lane & 15, quad = lane >> 4;
  int wm = (wave & 1) * 64, wn = (wave >> 1) * 64;
  f32x4 zero = {0.f, 0.f, 0.f, 0.f};
  f32x4 acc[4][4];
  for (int mt = 0; mt < 4; ++mt) for (int nt = 0; nt < 4; ++nt) acc[mt][nt] = zero;

  int sr = t >> 1, sc = (t & 1) * 32;
  const float* aptr = A + (size_t)(m0 + sr) * D_MODEL + sc;
  // async-B lane mapping: 8 rows x 128B per instr, lane l -> row l>>3, col (l&7)*8
  const unsigned short* bsrc = Bt + (size_t)(n0 + wave * 32 + (lane >> 3)) * D_MODEL + (lane & 7) * 8;
  unsigned short* bdst = Bs + wave * 32 * 64 + lane * 8;

  for (int k0 = 0; k0 < D_MODEL; k0 += 64) {
    __syncthreads();
#pragma unroll
    for (int i = 0; i < 4; ++i)                      // B: 4 async 1KB DMAs per wave
      gll16(bsrc + k0 + (size_t)i * 8 * D_MODEL, bdst + i * 512);
#pragma unroll
    for (int j = 0; j < 4; ++j) {                    // A: load fp32, convert, ds_write
      float4 x0 = *(const float4*)(aptr + k0 + j * 8);
      float4 x1 = *(const float4*)(aptr + k0 + j * 8 + 4);
      int4 w;
      w.x = pk2(x0.x, x0.y); w.y = pk2(x0.z, x0.w);
      w.z = pk2(x1.x, x1.y); w.w = pk2(x1.z, x1.w);
      *(int4*)&As[sr * 72 + sc + j * 8] = w;
    }
    __syncthreads();                                 // drains lgkm + vmcnt (async B)
#pragma unroll
    for (int half = 0; half < 2; ++half) {
      bf16x8 a[4], b[4];
      for (int mt = 0; mt < 4; ++mt)
        a[mt] = *(const bf16x8*)&As[(wm + mt * 16 + l16) * 72 + half * 32 + quad * 8];
      for (int nt = 0; nt < 4; ++nt)
        b[nt] = *(const bf16x8*)&Bs[(wn + nt * 16 + l16) * 64 + half * 32 + quad * 8];
      for (int mt = 0; mt < 4; ++mt)
        for (int nt = 0; nt < 4; ++nt)
          acc[mt][nt] = __builtin_amdgcn_mfma_f32_16x16x32_bf16(a[mt], b[nt], acc[mt][nt], 0, 0, 0);
    }
  }

  if (z == 2) {
    // V: transpose through LDS (reuse SB), then coalesced dwordx4 stores.
    __syncthreads();
#pragma unroll
    for (int nt = 0; nt < 4; ++nt) {
      int col = wn + nt * 16 + l16;
      float bb = bv[n0 + col];
      for (int mt = 0; mt < 4; ++mt)
        for (int r = 0; r < 4; ++r)
          SB[col * 130 + wm + mt * 16 + quad * 4 + r] = f2b_rhu(acc[mt][nt][r] + bb);
    }
    __syncthreads();
    int c = t >> 1, hf = t & 1;                       // col in [0,128), row-half
    int colg = n0 + c, hh = colg >> 6, dd = colg & 63;
    int b_ = m0 >> 11, sbase = m0 & (SEQ - 1);
    unsigned short* dst = vt + (((size_t)(b_ * NHEAD + hh)) * DK + dd) * SEQ + sbase + hf * 64;
#pragma unroll
    for (int j = 0; j < 8; ++j)
      *(int4*)(dst + j * 8) = *(const int4*)&SB[c * 130 + hf * 64 + j * 8];
  } else if (z == 0) {
    // Q path: fold log2(e)/temperature into the projection output
    for (int nt = 0; nt < 4; ++nt) {
      int col = n0 + wn + nt * 16 + l16;
      float bb = bq[col];
      int h = col >> 6, d = col & 63;
      for (int mt = 0; mt < 4; ++mt)
        for (int r = 0; r < 4; ++r) {
          int row = m0 + wm + mt * 16 + quad * 4 + r;
          int b_ = row >> 11, s = row & (SEQ - 1);
          qh[(((size_t)(b_ * NHEAD + h) * SEQ) + s) * DK + d] =
              f2b_rhu((acc[mt][nt][r] + bb) * QSCALE);
        }
    }
  } else {
    for (int nt = 0; nt < 4; ++nt) {
      int col = n0 + wn + nt * 16 + l16;
      int h = col >> 6, d = col & 63;
      for (int mt = 0; mt < 4; ++mt)
        for (int r = 0; r < 4; ++r) {
          int row = m0 + wm + mt * 16 + quad * 4 + r;
          int b_ = row >> 11, s = row & (SEQ - 1);
          kh[(((size_t)(b_ * NHEAD + h) * SEQ) + s) * DK + d] = f2b_rhu(acc[mt][nt][r]);
        }
    }
  }
}

// ---- output projection GEMM: 64x64 tiles, both operands async global_load_lds ----
__global__ __launch_bounds__(256) void gemm_out_kernel(
    const unsigned short* __restrict__ A, const unsigned short* __restrict__ Bt,
    const float* __restrict__ bias, float* __restrict__ out) {
  __shared__ unsigned short As[64 * 64], Bs[64 * 64];
  int bid = blockIdx.x;
  int xcd = bid & 7, slot = bid >> 3;      // 128 slots per XCD
  int mi = slot & 7, n0 = (slot >> 3) * 64;
  int m0 = (mi * 8 + xcd) * 64;
  int t = threadIdx.x, lane = t & 63, wave = t >> 6;
  int l16 = lane & 15, quad = lane >> 4;
  int wm = (wave & 1) * 32, wn = (wave >> 1) * 32;
  f32x4 zero = {0.f, 0.f, 0.f, 0.f};
  f32x4 acc[2][2];
  for (int mt = 0; mt < 2; ++mt) for (int nt = 0; nt < 2; ++nt) acc[mt][nt] = zero;

  // wave covers 16 rows of each tile: 2 instrs x (8 rows x 128B)
  const unsigned short* asrc = A + (size_t)(m0 + wave * 16 + (lane >> 3)) * D_MODEL + (lane & 7) * 8;
  const unsigned short* bsrc = Bt + (size_t)(n0 + wave * 16 + (lane >> 3)) * D_MODEL + (lane & 7) * 8;
  unsigned short* adst = As + wave * 16 * 64 + lane * 8;
  unsigned short* bdst = Bs + wave * 16 * 64 + lane * 8;

  for (int k0 = 0; k0 < D_MODEL; k0 += 64) {
    __syncthreads();
#pragma unroll
    for (int i = 0; i < 2; ++i) {
      gll16(asrc + k0 + (size_t)i * 8 * D_MODEL, adst + i * 512);
      gll16(bsrc + k0 + (size_t)i * 8 * D_MODEL, bdst + i * 512);
    }
    __syncthreads();
#pragma unroll
    for (int half = 0; half < 2; ++half) {
      bf16x8 a[2], b[2];
      for (int mt = 0; mt < 2; ++mt)
        a[mt] = *(const bf16x8*)&As[(wm + mt * 16 + l16) * 64 + half * 32 + quad * 8];
      for (int nt = 0; nt < 2; ++nt)
        b[nt] = *(const bf16x8*)&Bs[(wn + nt * 16 + l16) * 64 + half * 32 + quad * 8];
      for (int mt = 0; mt < 2; ++mt)
        for (int nt = 0; nt < 2; ++nt)
          acc[mt][nt] = __builtin_amdgcn_mfma_f32_16x16x32_bf16(a[mt], b[nt], acc[mt][nt], 0, 0, 0);
    }
  }
  for (int nt = 0; nt < 2; ++nt) {
    int col = n0 + wn + nt * 16 + l16;
    float bb = bias[col];
    for (int mt = 0; mt < 2; ++mt)
      for (int r = 0; r < 4; ++r) {
        int row = m0 + wm + mt * 16 + quad * 4 + r;
        out[(size_t)row * D_MODEL + col] = acc[mt][nt][r] + bb;
      }
  }
}

// ---- flash attention (unchanged R6 body: proven). Q pre-scaled => exp2(s).
// Mask = sign-extend AND on packed bf16. Row-sums via MFMA ones-fragment.
// XCD-sticky (b,h): KV set (512 KB) stays in one XCD's L2. ----
__global__ __launch_bounds__(256) void attn_kernel(
    const unsigned short* __restrict__ qh, const unsigned short* __restrict__ kh,
    const unsigned short* __restrict__ vt, const unsigned long long* __restrict__ mbits,
    unsigned short* __restrict__ attb) {
  __shared__ unsigned short Qs[64 * 72], Ks[64 * 72], Vs[64 * 72];
  __shared__ unsigned short Ps[4][16 * 68];
  int bid = blockIdx.x;
  int xcd = bid & 7, slot = bid >> 3;        // 128 slots per XCD
  int bh_ = 4 * xcd + (slot >> 5);           // 4 (b,h) pairs per XCD
  int qt = slot & 31;
  int b = bh_ >> 4, h = bh_ & 15;
  int t = threadIdx.x, lane = t & 63, wave = t >> 6;
  int l16 = lane & 15, quad = lane >> 4;
  size_t bh = (size_t)b * NHEAD + h;

  int sr = t >> 2, sc = (t & 3) * 8;
  const unsigned short* Qg = qh + (bh * SEQ + (size_t)qt * 64) * DK;
  *(int4*)&Qs[sr * 72 + sc]      = *(const int4*)&Qg[sr * DK + sc];
  *(int4*)&Qs[sr * 72 + sc + 32] = *(const int4*)&Qg[sr * DK + sc + 32];
  __syncthreads();
  bf16x8 qf[2];
  qf[0] = *(const bf16x8*)&Qs[(wave * 16 + l16) * 72 + quad * 8];
  qf[1] = *(const bf16x8*)&Qs[(wave * 16 + l16) * 72 + 32 + quad * 8];
  unsigned short* Pw = Ps[wave];

  const unsigned short* Kg = kh + bh * SEQ * DK;
  const unsigned short* Vg = vt + bh * DK * SEQ;
  const unsigned long long* mrow = mbits + (size_t)b * SEQ * (SEQ / 64);
  int qrow0 = qt * 64 + wave * 16 + quad * 4;

  bf16x8 ones;
#pragma unroll
  for (int i = 0; i < 8; ++i) ones[i] = (short)0x3F80;  // bf16 1.0

  f32x4 zero = {0.f, 0.f, 0.f, 0.f};
  f32x4 accO[4], accRS = zero;
  for (int nt = 0; nt < 4; ++nt) accO[nt] = zero;

  for (int tk = 0; tk < SEQ / 64; ++tk) {
    __syncthreads();
    {
      const unsigned short* Kt = Kg + (size_t)tk * 64 * DK;
      *(int4*)&Ks[sr * 72 + sc]      = *(const int4*)&Kt[sr * DK + sc];
      *(int4*)&Ks[sr * 72 + sc + 32] = *(const int4*)&Kt[sr * DK + sc + 32];
      const unsigned short* Vt_ = Vg + (size_t)tk * 64;
      *(int4*)&Vs[sr * 72 + sc]      = *(const int4*)&Vt_[(size_t)sr * SEQ + sc];
      *(int4*)&Vs[sr * 72 + sc + 32] = *(const int4*)&Vt_[(size_t)sr * SEQ + sc + 32];
    }
    __syncthreads();

    unsigned long long mw[4];
#pragma unroll
    for (int r = 0; r < 4; ++r)
      mw[r] = mrow[(size_t)(qrow0 + r) * (SEQ / 64) + tk] >> l16;

    f32x4 accS[4];
    for (int nt = 0; nt < 4; ++nt) accS[nt] = zero;
#pragma unroll
    for (int step = 0; step < 2; ++step)
      for (int nt = 0; nt < 4; ++nt) {
        bf16x8 bk = *(const bf16x8*)&Ks[(nt * 16 + l16) * 72 + step * 32 + quad * 8];
        accS[nt] = __builtin_amdgcn_mfma_f32_16x16x32_bf16(qf[step], bk, accS[nt], 0, 0, 0);
      }

#pragma unroll
    for (int r = 0; r < 4; ++r) {
      unsigned lo = (unsigned)mw[r], hi = (unsigned)(mw[r] >> 32);
#pragma unroll
      for (int nt = 0; nt < 4; ++nt) {
        unsigned halfw = (nt < 2) ? lo : hi;
        const int sh = 31 - ((nt & 1) * 16);
        float pv = __builtin_amdgcn_exp2f(accS[nt][r]);
        unsigned u = (__builtin_bit_cast(unsigned, pv) + 0x8000u) >> 16;
        int mskv = ((int)(halfw << sh)) >> 31;          // 0 or -1
        Pw[(quad * 4 + r) * 68 + nt * 16 + l16] = (unsigned short)(u & (unsigned)mskv);
      }
    }

#pragma unroll
    for (int step = 0; step < 2; ++step) {
      short4 plo = *(const short4*)&Pw[l16 * 68 + step * 32 + quad * 8];
      short4 phi = *(const short4*)&Pw[l16 * 68 + step * 32 + quad * 8 + 4];
      bf16x8 ap = {plo.x, plo.y, plo.z, plo.w, phi.x, phi.y, phi.z, phi.w};
      accRS = __builtin_amdgcn_mfma_f32_16x16x32_bf16(ap, ones, accRS, 0, 0, 0);
      for (int nt = 0; nt < 4; ++nt) {
        bf16x8 bv_ = *(const bf16x8*)&Vs[(nt * 16 + l16) * 72 + step * 32 + quad * 8];
        accO[nt] = __builtin_amdgcn_mfma_f32_16x16x32_bf16(ap, bv_, accO[nt], 0, 0, 0);
      }
    }
  }

  for (int r = 0; r < 4; ++r) {
    float sden = accRS[r];
    float inv = sden > 0.f ? 1.f / sden : 0.f;
    int row = qt * 64 + wave * 16 + quad * 4 + r;
    size_t ob = ((size_t)b * SEQ + row) * D_MODEL + (size_t)h * DK;
    for (int nt = 0; nt < 4; ++nt)
      attb[ob + nt * 16 + l16] = f2b_rhu(accO[nt][r] * inv);
  }
}

extern "C" void kernel_launch(void* const* d_in, const int* in_sizes, int n_in,
                              void* d_out, int out_size, void* d_ws, size_t ws_size,
                              hipStream_t stream) {
  (void)in_sizes; (void)n_in; (void)out_size; (void)ws_size;
  const float* q    = (const float*)d_in[0];
  const float* k    = (const float*)d_in[1];
  const float* v    = (const float*)d_in[2];
  const int*   mask = (const int*)d_in[3];
  const float* wq   = (const float*)d_in[4];
  const float* bq   = (const float*)d_in[5];
  const float* wk   = (const float*)d_in[6];
  const float* wv   = (const float*)d_in[7];
  const float* bv   = (const float*)d_in[8];
  const float* wf   = (const float*)d_in[9];
  const float* bf   = (const float*)d_in[10];

  char* ws = (char*)d_ws;
  // workspace layout (bytes) -- total ~36.7 MiB (proven safe; 73 MiB overflowed
  // in round 0 and corrupted the harness pristine buffers).
  // wqt/wkt/wvt dead after gemm_qkv; attb aliases them.
  unsigned short* wft  = (unsigned short*)(ws + 0);          // 2 MiB, live till end
  unsigned short* wqt  = (unsigned short*)(ws + 2097152);    // 2 MiB
  unsigned short* wkt  = (unsigned short*)(ws + 4194304);    // 2 MiB
  unsigned short* wvt  = (unsigned short*)(ws + 6291456);    // 2 MiB
  unsigned short* attb = (unsigned short*)(ws + 2097152);    // 8 MiB alias
  unsigned short* qhp  = (unsigned short*)(ws + 10485760);   // 8 MiB
  unsigned short* khp  = (unsigned short*)(ws + 18874368);   // 8 MiB
  unsigned short* vtp  = (unsigned short*)(ws + 27262976);   // 8 MiB
  unsigned long long* mbits = (unsigned long long*)(ws + 35651584); // 1 MiB

  hipLaunchKernelGGL(wtrans_kernel, dim3(16, 16, 4), dim3(256), 0, stream,
                     wq, wk, wv, wf, wqt, wkt, wvt, wft);
  hipLaunchKernelGGL(maskpack_kernel, dim3(32768), dim3(256), 0, stream, mask, mbits);
  hipLaunchKernelGGL(gemm_qkv_kernel, dim3(768), dim3(256), 0, stream,
                     q, k, v, wqt, wkt, wvt, bq, bv, qhp, khp, vtp);
  hipLaunchKernelGGL(attn_kernel, dim3(1024), dim3(256), 0, stream,
                     qhp, khp, vtp, mbits, attb);
  hipLaunchKernelGGL(gemm_out_kernel, dim3(1024), dim3(256), 0, stream,
                     attb, wft, bf, (float*)d_out);
}

// Round 8
// 307.299 us; speedup vs baseline: 1.6052x; 1.0474x over previous
//
#include <hip/hip_runtime.h>

// ---- problem constants ----
#define D_MODEL 1024
#define NHEAD   16
#define DK      64
#define BATCH   2
#define SEQ     2048

typedef __attribute__((ext_vector_type(8))) short bf16x8;
typedef __attribute__((ext_vector_type(4))) float f32x4;

#define QSCALE 0.18033688011f   // log2(e) / sqrt(64): folded into Q projection

__device__ __forceinline__ unsigned short f2b(float x) {
  unsigned u = __builtin_bit_cast(unsigned, x);
  u = (u + 0x7fffu + ((u >> 16) & 1u)) >> 16;   // RNE to bf16
  return (unsigned short)u;
}
// round-half-up bf16 (bias 2^-17 rel, error <= 2^-9 like RNE) -- 1 add
__device__ __forceinline__ unsigned short f2b_rhu(float x) {
  return (unsigned short)((__builtin_bit_cast(unsigned, x) + 0x8000u) >> 16);
}
// pack two fp32 -> two bf16 (round-half-up) in 3 VALU: add, add, v_perm
__device__ __forceinline__ int pk2(float a, float b) {
  unsigned ua = __builtin_bit_cast(unsigned, a) + 0x8000u;
  unsigned ub = __builtin_bit_cast(unsigned, b) + 0x8000u;
  return (int)__builtin_amdgcn_perm(ub, ua, 0x07060302u);  // [ub.hi16 : ua.hi16]
}

// async 16B global->LDS (m97 pattern). LDS dest = wave-uniform base + lane*16.
typedef const __attribute__((address_space(1))) void* gas_p;
typedef __attribute__((address_space(3))) void* las_p;
__device__ __forceinline__ void gll16(const void* g, void* l) {
  __builtin_amdgcn_global_load_lds((gas_p)g, (las_p)l, 16, 0, 0);
}

// ---- cast q,k,v fp32 -> bf16 (qb/kb live in d_out scratch, vb in ws) ----
__global__ __launch_bounds__(256) void cast3_kernel(
    const float* __restrict__ q, const float* __restrict__ k, const float* __restrict__ v,
    unsigned short* __restrict__ qb, unsigned short* __restrict__ kb,
    unsigned short* __restrict__ vb) {
  const float* src = blockIdx.y == 0 ? q : (blockIdx.y == 1 ? k : v);
  unsigned short* dst = blockIdx.y == 0 ? qb : (blockIdx.y == 1 ? kb : vb);
  size_t i = ((size_t)blockIdx.x * 256 + threadIdx.x) * 8;
  float4 x0 = *(const float4*)&src[i];
  float4 x1 = *(const float4*)&src[i + 4];
  int4 w;
  w.x = pk2(x0.x, x0.y); w.y = pk2(x0.z, x0.w);
  w.z = pk2(x1.x, x1.y); w.w = pk2(x1.z, x1.w);
  *(int4*)&dst[i] = w;
}

// ---- transpose + cast weights: w[in][out] fp32 -> wt[out][in] bf16 ----
__global__ __launch_bounds__(256) void wtrans_kernel(
    const float* __restrict__ wq, const float* __restrict__ wk,
    const float* __restrict__ wv, const float* __restrict__ wf,
    unsigned short* __restrict__ wqt, unsigned short* __restrict__ wkt,
    unsigned short* __restrict__ wvt, unsigned short* __restrict__ wft) {
  __shared__ float tile[64][65];
  const float* w; unsigned short* wt;
  switch (blockIdx.z) {
    case 0: w = wq; wt = wqt; break;
    case 1: w = wk; wt = wkt; break;
    case 2: w = wv; wt = wvt; break;
    default: w = wf; wt = wft; break;
  }
  int r0 = blockIdx.y * 64, c0 = blockIdx.x * 64;
  int t = threadIdx.x;
  for (int i = 0; i < 16; ++i) {
    int idx = t + i * 256; int r = idx >> 6, c = idx & 63;
    tile[r][c] = w[(size_t)(r0 + r) * D_MODEL + c0 + c];
  }
  __syncthreads();
  for (int i = 0; i < 16; ++i) {
    int idx = t + i * 256; int r = idx >> 6, c = idx & 63;
    wt[(size_t)(c0 + r) * D_MODEL + r0 + c] = f2b(tile[c][r]);
  }
}

// ---- pack mask int32 -> bit-words (bit lane = mask!=0), one u64 per 64 keys ----
__global__ __launch_bounds__(256) void maskpack_kernel(
    const int* __restrict__ mask, unsigned long long* __restrict__ mbits) {
  size_t gw = ((size_t)blockIdx.x * 256 + threadIdx.x) >> 6;
  int lane = threadIdx.x & 63;
  int val = mask[gw * 64 + lane];
  unsigned long long bits = __ballot(val != 0);
  if (lane == 0) mbits[gw] = bits;
}

// ---- fused QKV projection GEMM, pure-m97 staging: BOTH operands via async
// global_load_lds dwordx4, zero staging VALU (A pre-cast to bf16 by cast3).
// 128x128 tile, BK=64 stored as two stacked 64B-row halves (m97 geometry).
// XCD-sticky mapping keeps A/B panels L2-local (R6: FETCH 203->49 MB). ----
__global__ __launch_bounds__(256) void gemm_qkv_kernel(
    const unsigned short* __restrict__ qb, const unsigned short* __restrict__ kb,
    const unsigned short* __restrict__ vb,
    const unsigned short* __restrict__ wqt, const unsigned short* __restrict__ wkt,
    const unsigned short* __restrict__ wvt,
    const float* __restrict__ bq, const float* __restrict__ bv,
    unsigned short* __restrict__ qh, unsigned short* __restrict__ kh,
    unsigned short* __restrict__ vt) {
  __shared__ unsigned short SB[16640];     // As[0..8192) + Bs[8192..16384); V-transpose alias
  unsigned short* As = SB;                 // halves at 0, 4096 (each 128 rows x 32 cols)
  unsigned short* Bs = SB + 8192;
  int bid = blockIdx.x;
  int xcd = bid & 7, slot = bid >> 3;      // 96 slots per XCD
  int mi = slot & 3, zn = slot >> 2;       // 4 m-panels per XCD, zn in [0,24)
  int z = zn >> 3;
  int n0 = (zn & 7) * 128;
  int m0 = (mi * 8 + xcd) * 128;
  const unsigned short* A; const unsigned short* Bt;
  switch (z) {
    case 0:  A = qb; Bt = wqt; break;
    case 1:  A = kb; Bt = wkt; break;
    default: A = vb; Bt = wvt; break;
  }
  int t = threadIdx.x, lane = t & 63, wave = t >> 6;
  int l16 = lane & 15, quad = lane >> 4;
  int wm = (wave & 1) * 64, wn = (wave >> 1) * 64;
  f32x4 zero = {0.f, 0.f, 0.f, 0.f};
  f32x4 acc[4][4];
  for (int mt = 0; mt < 4; ++mt) for (int nt = 0; nt < 4; ++nt) acc[mt][nt] = zero;

  // DMA lane mapping: row = lane>>2 (16 rows/instr), col = (lane&3)*8 ushorts;
  // LDS dst offset = row*64B + (lane&3)*16B = lane*16B (contiguous, required).
  int drow = lane >> 2, dcol = (lane & 3) * 8;
  const unsigned short* asrc = A  + (size_t)(m0 + wave * 32 + drow) * D_MODEL + dcol;
  const unsigned short* bsrc = Bt + (size_t)(n0 + wave * 32 + drow) * D_MODEL + dcol;
  unsigned short* adst = As + wave * 32 * 32 + lane * 8;   // +half*4096, +grp*512
  unsigned short* bdst = Bs + wave * 32 * 32 + lane * 8;

  for (int k0 = 0; k0 < D_MODEL; k0 += 64) {
    __syncthreads();
#pragma unroll
    for (int g = 0; g < 2; ++g)            // row-group (16 rows each)
#pragma unroll
      for (int hf = 0; hf < 2; ++hf) {     // k-half (32 cols each)
        gll16(asrc + (size_t)(g * 16) * D_MODEL + k0 + hf * 32, adst + hf * 4096 + g * 512);
        gll16(bsrc + (size_t)(g * 16) * D_MODEL + k0 + hf * 32, bdst + hf * 4096 + g * 512);
      }
    __syncthreads();                       // drains the 8 DMAs (vmcnt)
#pragma unroll
    for (int half = 0; half < 2; ++half) {
      bf16x8 a[4], b[4];
      for (int mt = 0; mt < 4; ++mt)
        a[mt] = *(const bf16x8*)&As[half * 4096 + (wm + mt * 16 + l16) * 32 + quad * 8];
      for (int nt = 0; nt < 4; ++nt)
        b[nt] = *(const bf16x8*)&Bs[half * 4096 + (wn + nt * 16 + l16) * 32 + quad * 8];
      for (int mt = 0; mt < 4; ++mt)
        for (int nt = 0; nt < 4; ++nt)
          acc[mt][nt] = __builtin_amdgcn_mfma_f32_16x16x32_bf16(a[mt], b[nt], acc[mt][nt], 0, 0, 0);
    }
  }

  if (z == 2) {
    // V: transpose through LDS (reuse SB), then coalesced dwordx4 stores.
    __syncthreads();
#pragma unroll
    for (int nt = 0; nt < 4; ++nt) {
      int col = wn + nt * 16 + l16;
      float bb = bv[n0 + col];
      for (int mt = 0; mt < 4; ++mt)
        for (int r = 0; r < 4; ++r)
          SB[col * 130 + wm + mt * 16 + quad * 4 + r] = f2b_rhu(acc[mt][nt][r] + bb);
    }
    __syncthreads();
    int c = t >> 1, hf = t & 1;
    int colg = n0 + c, hh = colg >> 6, dd = colg & 63;
    int b_ = m0 >> 11, sbase = m0 & (SEQ - 1);
    unsigned short* dst = vt + (((size_t)(b_ * NHEAD + hh)) * DK + dd) * SEQ + sbase + hf * 64;
#pragma unroll
    for (int j = 0; j < 8; ++j)
      *(int4*)(dst + j * 8) = *(const int4*)&SB[c * 130 + hf * 64 + j * 8];
  } else if (z == 0) {
    for (int nt = 0; nt < 4; ++nt) {
      int col = n0 + wn + nt * 16 + l16;
      float bb = bq[col];
      int h = col >> 6, d = col & 63;
      for (int mt = 0; mt < 4; ++mt)
        for (int r = 0; r < 4; ++r) {
          int row = m0 + wm + mt * 16 + quad * 4 + r;
          int b_ = row >> 11, s = row & (SEQ - 1);
          qh[(((size_t)(b_ * NHEAD + h) * SEQ) + s) * DK + d] =
              f2b_rhu((acc[mt][nt][r] + bb) * QSCALE);
        }
    }
  } else {
    for (int nt = 0; nt < 4; ++nt) {
      int col = n0 + wn + nt * 16 + l16;
      int h = col >> 6, d = col & 63;
      for (int mt = 0; mt < 4; ++mt)
        for (int r = 0; r < 4; ++r) {
          int row = m0 + wm + mt * 16 + quad * 4 + r;
          int b_ = row >> 11, s = row & (SEQ - 1);
          kh[(((size_t)(b_ * NHEAD + h) * SEQ) + s) * DK + d] = f2b_rhu(acc[mt][nt][r]);
        }
    }
  }
}

// ---- output projection GEMM: 64x64 tiles, both operands async global_load_lds ----
__global__ __launch_bounds__(256) void gemm_out_kernel(
    const unsigned short* __restrict__ A, const unsigned short* __restrict__ Bt,
    const float* __restrict__ bias, float* __restrict__ out) {
  __shared__ unsigned short As[64 * 64], Bs[64 * 64];
  int bid = blockIdx.x;
  int xcd = bid & 7, slot = bid >> 3;      // 128 slots per XCD
  int mi = slot & 7, n0 = (slot >> 3) * 64;
  int m0 = (mi * 8 + xcd) * 64;
  int t = threadIdx.x, lane = t & 63, wave = t >> 6;
  int l16 = lane & 15, quad = lane >> 4;
  int wm = (wave & 1) * 32, wn = (wave >> 1) * 32;
  f32x4 zero = {0.f, 0.f, 0.f, 0.f};
  f32x4 acc[2][2];
  for (int mt = 0; mt < 2; ++mt) for (int nt = 0; nt < 2; ++nt) acc[mt][nt] = zero;

  const unsigned short* asrc = A + (size_t)(m0 + wave * 16 + (lane >> 3)) * D_MODEL + (lane & 7) * 8;
  const unsigned short* bsrc = Bt + (size_t)(n0 + wave * 16 + (lane >> 3)) * D_MODEL + (lane & 7) * 8;
  unsigned short* adst = As + wave * 16 * 64 + lane * 8;
  unsigned short* bdst = Bs + wave * 16 * 64 + lane * 8;

  for (int k0 = 0; k0 < D_MODEL; k0 += 64) {
    __syncthreads();
#pragma unroll
    for (int i = 0; i < 2; ++i) {
      gll16(asrc + k0 + (size_t)i * 8 * D_MODEL, adst + i * 512);
      gll16(bsrc + k0 + (size_t)i * 8 * D_MODEL, bdst + i * 512);
    }
    __syncthreads();
#pragma unroll
    for (int half = 0; half < 2; ++half) {
      bf16x8 a[2], b[2];
      for (int mt = 0; mt < 2; ++mt)
        a[mt] = *(const bf16x8*)&As[(wm + mt * 16 + l16) * 64 + half * 32 + quad * 8];
      for (int nt = 0; nt < 2; ++nt)
        b[nt] = *(const bf16x8*)&Bs[(wn + nt * 16 + l16) * 64 + half * 32 + quad * 8];
      for (int mt = 0; mt < 2; ++mt)
        for (int nt = 0; nt < 2; ++nt)
          acc[mt][nt] = __builtin_amdgcn_mfma_f32_16x16x32_bf16(a[mt], b[nt], acc[mt][nt], 0, 0, 0);
    }
  }
  for (int nt = 0; nt < 2; ++nt) {
    int col = n0 + wn + nt * 16 + l16;
    float bb = bias[col];
    for (int mt = 0; mt < 2; ++mt)
      for (int r = 0; r < 4; ++r) {
        int row = m0 + wm + mt * 16 + quad * 4 + r;
        out[(size_t)row * D_MODEL + col] = acc[mt][nt][r] + bb;
      }
  }
}

// ---- flash attention (unchanged: proven). Q pre-scaled => exp2(s).
// Mask = sign-extend AND on packed bf16. Row-sums via MFMA ones-fragment. ----
__global__ __launch_bounds__(256) void attn_kernel(
    const unsigned short* __restrict__ qh, const unsigned short* __restrict__ kh,
    const unsigned short* __restrict__ vt, const unsigned long long* __restrict__ mbits,
    unsigned short* __restrict__ attb) {
  __shared__ unsigned short Qs[64 * 72], Ks[64 * 72], Vs[64 * 72];
  __shared__ unsigned short Ps[4][16 * 68];
  int bid = blockIdx.x;
  int xcd = bid & 7, slot = bid >> 3;
  int bh_ = 4 * xcd + (slot >> 5);
  int qt = slot & 31;
  int b = bh_ >> 4, h = bh_ & 15;
  int t = threadIdx.x, lane = t & 63, wave = t >> 6;
  int l16 = lane & 15, quad = lane >> 4;
  size_t bh = (size_t)b * NHEAD + h;

  int sr = t >> 2, sc = (t & 3) * 8;
  const unsigned short* Qg = qh + (bh * SEQ + (size_t)qt * 64) * DK;
  *(int4*)&Qs[sr * 72 + sc]      = *(const int4*)&Qg[sr * DK + sc];
  *(int4*)&Qs[sr * 72 + sc + 32] = *(const int4*)&Qg[sr * DK + sc + 32];
  __syncthreads();
  bf16x8 qf[2];
  qf[0] = *(const bf16x8*)&Qs[(wave * 16 + l16) * 72 + quad * 8];
  qf[1] = *(const bf16x8*)&Qs[(wave * 16 + l16) * 72 + 32 + quad * 8];
  unsigned short* Pw = Ps[wave];

  const unsigned short* Kg = kh + bh * SEQ * DK;
  const unsigned short* Vg = vt + bh * DK * SEQ;
  const unsigned long long* mrow = mbits + (size_t)b * SEQ * (SEQ / 64);
  int qrow0 = qt * 64 + wave * 16 + quad * 4;

  bf16x8 ones;
#pragma unroll
  for (int i = 0; i < 8; ++i) ones[i] = (short)0x3F80;

  f32x4 zero = {0.f, 0.f, 0.f, 0.f};
  f32x4 accO[4], accRS = zero;
  for (int nt = 0; nt < 4; ++nt) accO[nt] = zero;

  for (int tk = 0; tk < SEQ / 64; ++tk) {
    __syncthreads();
    {
      const unsigned short* Kt = Kg + (size_t)tk * 64 * DK;
      *(int4*)&Ks[sr * 72 + sc]      = *(const int4*)&Kt[sr * DK + sc];
      *(int4*)&Ks[sr * 72 + sc + 32] = *(const int4*)&Kt[sr * DK + sc + 32];
      const unsigned short* Vt_ = Vg + (size_t)tk * 64;
      *(int4*)&Vs[sr * 72 + sc]      = *(const int4*)&Vt_[(size_t)sr * SEQ + sc];
      *(int4*)&Vs[sr * 72 + sc + 32] = *(const int4*)&Vt_[(size_t)sr * SEQ + sc + 32];
    }
    __syncthreads();

    unsigned long long mw[4];
#pragma unroll
    for (int r = 0; r < 4; ++r)
      mw[r] = mrow[(size_t)(qrow0 + r) * (SEQ / 64) + tk] >> l16;

    f32x4 accS[4];
    for (int nt = 0; nt < 4; ++nt) accS[nt] = zero;
#pragma unroll
    for (int step = 0; step < 2; ++step)
      for (int nt = 0; nt < 4; ++nt) {
        bf16x8 bk = *(const bf16x8*)&Ks[(nt * 16 + l16) * 72 + step * 32 + quad * 8];
        accS[nt] = __builtin_amdgcn_mfma_f32_16x16x32_bf16(qf[step], bk, accS[nt], 0, 0, 0);
      }

#pragma unroll
    for (int r = 0; r < 4; ++r) {
      unsigned lo = (unsigned)mw[r], hi = (unsigned)(mw[r] >> 32);
#pragma unroll
      for (int nt = 0; nt < 4; ++nt) {
        unsigned halfw = (nt < 2) ? lo : hi;
        const int sh = 31 - ((nt & 1) * 16);
        float pv = __builtin_amdgcn_exp2f(accS[nt][r]);
        unsigned u = (__builtin_bit_cast(unsigned, pv) + 0x8000u) >> 16;
        int mskv = ((int)(halfw << sh)) >> 31;
        Pw[(quad * 4 + r) * 68 + nt * 16 + l16] = (unsigned short)(u & (unsigned)mskv);
      }
    }

#pragma unroll
    for (int step = 0; step < 2; ++step) {
      short4 plo = *(const short4*)&Pw[l16 * 68 + step * 32 + quad * 8];
      short4 phi = *(const short4*)&Pw[l16 * 68 + step * 32 + quad * 8 + 4];
      bf16x8 ap = {plo.x, plo.y, plo.z, plo.w, phi.x, phi.y, phi.z, phi.w};
      accRS = __builtin_amdgcn_mfma_f32_16x16x32_bf16(ap, ones, accRS, 0, 0, 0);
      for (int nt = 0; nt < 4; ++nt) {
        bf16x8 bv_ = *(const bf16x8*)&Vs[(nt * 16 + l16) * 72 + step * 32 + quad * 8];
        accO[nt] = __builtin_amdgcn_mfma_f32_16x16x32_bf16(ap, bv_, accO[nt], 0, 0, 0);
      }
    }
  }

  for (int r = 0; r < 4; ++r) {
    float sden = accRS[r];
    float inv = sden > 0.f ? 1.f / sden : 0.f;
    int row = qt * 64 + wave * 16 + quad * 4 + r;
    size_t ob = ((size_t)b * SEQ + row) * D_MODEL + (size_t)h * DK;
    for (int nt = 0; nt < 4; ++nt)
      attb[ob + nt * 16 + l16] = f2b_rhu(accO[nt][r] * inv);
  }
}

extern "C" void kernel_launch(void* const* d_in, const int* in_sizes, int n_in,
                              void* d_out, int out_size, void* d_ws, size_t ws_size,
                              hipStream_t stream) {
  (void)in_sizes; (void)n_in; (void)out_size; (void)ws_size;
  const float* q    = (const float*)d_in[0];
  const float* k    = (const float*)d_in[1];
  const float* v    = (const float*)d_in[2];
  const int*   mask = (const int*)d_in[3];
  const float* wq   = (const float*)d_in[4];
  const float* bq   = (const float*)d_in[5];
  const float* wk   = (const float*)d_in[6];
  const float* wv   = (const float*)d_in[7];
  const float* bv   = (const float*)d_in[8];
  const float* wf   = (const float*)d_in[9];
  const float* bf   = (const float*)d_in[10];

  char* ws = (char*)d_ws;
  // workspace layout (bytes) -- ~44.7 MiB total (36.7 proven safe, 76.5 known
  // bad). d_out (16 MiB fp32, only read after gemm_out) doubles as scratch
  // for q_bf16 + k_bf16; only v_bf16 lives in new ws space.
  unsigned short* wft  = (unsigned short*)(ws + 0);          // 2 MiB, live till end
  unsigned short* wqt  = (unsigned short*)(ws + 2097152);    // 2 MiB
  unsigned short* wkt  = (unsigned short*)(ws + 4194304);    // 2 MiB
  unsigned short* wvt  = (unsigned short*)(ws + 6291456);    // 2 MiB
  unsigned short* attb = (unsigned short*)(ws + 2097152);    // 8 MiB alias (wqt/wkt/wvt dead)
  unsigned short* qhp  = (unsigned short*)(ws + 10485760);   // 8 MiB
  unsigned short* khp  = (unsigned short*)(ws + 18874368);   // 8 MiB
  unsigned short* vtp  = (unsigned short*)(ws + 27262976);   // 8 MiB
  unsigned long long* mbits = (unsigned long long*)(ws + 35651584); // 1 MiB
  unsigned short* vb   = (unsigned short*)(ws + 36700160);   // 8 MiB
  unsigned short* qb   = (unsigned short*)d_out;             // 8 MiB (scratch in d_out)
  unsigned short* kb   = (unsigned short*)d_out + 4194304;   // 8 MiB

  hipLaunchKernelGGL(cast3_kernel, dim3(2048, 3), dim3(256), 0, stream, q, k, v, qb, kb, vb);
  hipLaunchKernelGGL(wtrans_kernel, dim3(16, 16, 4), dim3(256), 0, stream,
                     wq, wk, wv, wf, wqt, wkt, wvt, wft);
  hipLaunchKernelGGL(maskpack_kernel, dim3(32768), dim3(256), 0, stream, mask, mbits);
  hipLaunchKernelGGL(gemm_qkv_kernel, dim3(768), dim3(256), 0, stream,
                     qb, kb, vb, wqt, wkt, wvt, bq, bv, qhp, khp, vtp);
  hipLaunchKernelGGL(attn_kernel, dim3(1024), dim3(256), 0, stream,
                     qhp, khp, vtp, mbits, attb);
  hipLaunchKernelGGL(gemm_out_kernel, dim3(1024), dim3(256), 0, stream,
                     attb, wft, bf, (float*)d_out);
}

// Round 9
// 300.583 us; speedup vs baseline: 1.6411x; 1.0223x over previous
//
#include <hip/hip_runtime.h>

// ---- problem constants ----
#define D_MODEL 1024
#define NHEAD   16
#define DK      64
#define BATCH   2
#define SEQ     2048

typedef __attribute__((ext_vector_type(8))) short bf16x8;
typedef __attribute__((ext_vector_type(4))) float f32x4;

#define QSCALE 0.18033688011f   // log2(e) / sqrt(64): folded into Q projection

__device__ __forceinline__ unsigned short f2b(float x) {
  unsigned u = __builtin_bit_cast(unsigned, x);
  u = (u + 0x7fffu + ((u >> 16) & 1u)) >> 16;   // RNE to bf16
  return (unsigned short)u;
}
// round-half-up bf16 (bias 2^-17 rel, error <= 2^-9 like RNE) -- 1 add
__device__ __forceinline__ unsigned short f2b_rhu(float x) {
  return (unsigned short)((__builtin_bit_cast(unsigned, x) + 0x8000u) >> 16);
}
// pack two fp32 -> two bf16 (round-half-up) in 3 VALU: add, add, v_perm
__device__ __forceinline__ int pk2(float a, float b) {
  unsigned ua = __builtin_bit_cast(unsigned, a) + 0x8000u;
  unsigned ub = __builtin_bit_cast(unsigned, b) + 0x8000u;
  return (int)__builtin_amdgcn_perm(ub, ua, 0x07060302u);  // [ub.hi16 : ua.hi16]
}

// async 16B global->LDS (m97 pattern). LDS dest = wave-uniform base + lane*16.
typedef const __attribute__((address_space(1))) void* gas_p;
typedef __attribute__((address_space(3))) void* las_p;
__device__ __forceinline__ void gll16(const void* g, void* l) {
  __builtin_amdgcn_global_load_lds((gas_p)g, (las_p)l, 16, 0, 0);
}

// ---- cast q,k,v fp32 -> bf16 (qb/kb live in d_out scratch, vb in ws) ----
__global__ __launch_bounds__(256) void cast3_kernel(
    const float* __restrict__ q, const float* __restrict__ k, const float* __restrict__ v,
    unsigned short* __restrict__ qb, unsigned short* __restrict__ kb,
    unsigned short* __restrict__ vb) {
  const float* src = blockIdx.y == 0 ? q : (blockIdx.y == 1 ? k : v);
  unsigned short* dst = blockIdx.y == 0 ? qb : (blockIdx.y == 1 ? kb : vb);
  size_t i = ((size_t)blockIdx.x * 256 + threadIdx.x) * 8;
  float4 x0 = *(const float4*)&src[i];
  float4 x1 = *(const float4*)&src[i + 4];
  int4 w;
  w.x = pk2(x0.x, x0.y); w.y = pk2(x0.z, x0.w);
  w.z = pk2(x1.x, x1.y); w.w = pk2(x1.z, x1.w);
  *(int4*)&dst[i] = w;
}

// ---- transpose + cast weights: w[in][out] fp32 -> wt[out][in] bf16 ----
__global__ __launch_bounds__(256) void wtrans_kernel(
    const float* __restrict__ wq, const float* __restrict__ wk,
    const float* __restrict__ wv, const float* __restrict__ wf,
    unsigned short* __restrict__ wqt, unsigned short* __restrict__ wkt,
    unsigned short* __restrict__ wvt, unsigned short* __restrict__ wft) {
  __shared__ float tile[64][65];
  const float* w; unsigned short* wt;
  switch (blockIdx.z) {
    case 0: w = wq; wt = wqt; break;
    case 1: w = wk; wt = wkt; break;
    case 2: w = wv; wt = wvt; break;
    default: w = wf; wt = wft; break;
  }
  int r0 = blockIdx.y * 64, c0 = blockIdx.x * 64;
  int t = threadIdx.x;
  for (int i = 0; i < 16; ++i) {
    int idx = t + i * 256; int r = idx >> 6, c = idx & 63;
    tile[r][c] = w[(size_t)(r0 + r) * D_MODEL + c0 + c];
  }
  __syncthreads();
  for (int i = 0; i < 16; ++i) {
    int idx = t + i * 256; int r = idx >> 6, c = idx & 63;
    wt[(size_t)(c0 + r) * D_MODEL + r0 + c] = f2b(tile[c][r]);
  }
}

// ---- pack mask int32 -> bit-words (bit lane = mask!=0), one u64 per 64 keys ----
__global__ __launch_bounds__(256) void maskpack_kernel(
    const int* __restrict__ mask, unsigned long long* __restrict__ mbits) {
  size_t gw = ((size_t)blockIdx.x * 256 + threadIdx.x) >> 6;
  int lane = threadIdx.x & 63;
  int val = mask[gw * 64 + lane];
  unsigned long long bits = __ballot(val != 0);
  if (lane == 0) mbits[gw] = bits;
}

// ---- fused QKV projection GEMM, pure-m97 staging (unchanged from R8) ----
__global__ __launch_bounds__(256) void gemm_qkv_kernel(
    const unsigned short* __restrict__ qb, const unsigned short* __restrict__ kb,
    const unsigned short* __restrict__ vb,
    const unsigned short* __restrict__ wqt, const unsigned short* __restrict__ wkt,
    const unsigned short* __restrict__ wvt,
    const float* __restrict__ bq, const float* __restrict__ bv,
    unsigned short* __restrict__ qh, unsigned short* __restrict__ kh,
    unsigned short* __restrict__ vt) {
  __shared__ unsigned short SB[16640];     // As[0..8192) + Bs[8192..16384); V-transpose alias
  unsigned short* As = SB;                 // halves at 0, 4096 (each 128 rows x 32 cols)
  unsigned short* Bs = SB + 8192;
  int bid = blockIdx.x;
  int xcd = bid & 7, slot = bid >> 3;      // 96 slots per XCD
  int mi = slot & 3, zn = slot >> 2;       // 4 m-panels per XCD, zn in [0,24)
  int z = zn >> 3;
  int n0 = (zn & 7) * 128;
  int m0 = (mi * 8 + xcd) * 128;
  const unsigned short* A; const unsigned short* Bt;
  switch (z) {
    case 0:  A = qb; Bt = wqt; break;
    case 1:  A = kb; Bt = wkt; break;
    default: A = vb; Bt = wvt; break;
  }
  int t = threadIdx.x, lane = t & 63, wave = t >> 6;
  int l16 = lane & 15, quad = lane >> 4;
  int wm = (wave & 1) * 64, wn = (wave >> 1) * 64;
  f32x4 zero = {0.f, 0.f, 0.f, 0.f};
  f32x4 acc[4][4];
  for (int mt = 0; mt < 4; ++mt) for (int nt = 0; nt < 4; ++nt) acc[mt][nt] = zero;

  int drow = lane >> 2, dcol = (lane & 3) * 8;
  const unsigned short* asrc = A  + (size_t)(m0 + wave * 32 + drow) * D_MODEL + dcol;
  const unsigned short* bsrc = Bt + (size_t)(n0 + wave * 32 + drow) * D_MODEL + dcol;
  unsigned short* adst = As + wave * 32 * 32 + lane * 8;
  unsigned short* bdst = Bs + wave * 32 * 32 + lane * 8;

  for (int k0 = 0; k0 < D_MODEL; k0 += 64) {
    __syncthreads();
#pragma unroll
    for (int g = 0; g < 2; ++g)
#pragma unroll
      for (int hf = 0; hf < 2; ++hf) {
        gll16(asrc + (size_t)(g * 16) * D_MODEL + k0 + hf * 32, adst + hf * 4096 + g * 512);
        gll16(bsrc + (size_t)(g * 16) * D_MODEL + k0 + hf * 32, bdst + hf * 4096 + g * 512);
      }
    __syncthreads();
#pragma unroll
    for (int half = 0; half < 2; ++half) {
      bf16x8 a[4], b[4];
      for (int mt = 0; mt < 4; ++mt)
        a[mt] = *(const bf16x8*)&As[half * 4096 + (wm + mt * 16 + l16) * 32 + quad * 8];
      for (int nt = 0; nt < 4; ++nt)
        b[nt] = *(const bf16x8*)&Bs[half * 4096 + (wn + nt * 16 + l16) * 32 + quad * 8];
      for (int mt = 0; mt < 4; ++mt)
        for (int nt = 0; nt < 4; ++nt)
          acc[mt][nt] = __builtin_amdgcn_mfma_f32_16x16x32_bf16(a[mt], b[nt], acc[mt][nt], 0, 0, 0);
    }
  }

  if (z == 2) {
    __syncthreads();
#pragma unroll
    for (int nt = 0; nt < 4; ++nt) {
      int col = wn + nt * 16 + l16;
      float bb = bv[n0 + col];
      for (int mt = 0; mt < 4; ++mt)
        for (int r = 0; r < 4; ++r)
          SB[col * 130 + wm + mt * 16 + quad * 4 + r] = f2b_rhu(acc[mt][nt][r] + bb);
    }
    __syncthreads();
    int c = t >> 1, hf = t & 1;
    int colg = n0 + c, hh = colg >> 6, dd = colg & 63;
    int b_ = m0 >> 11, sbase = m0 & (SEQ - 1);
    unsigned short* dst = vt + (((size_t)(b_ * NHEAD + hh)) * DK + dd) * SEQ + sbase + hf * 64;
#pragma unroll
    for (int j = 0; j < 8; ++j)
      *(int4*)(dst + j * 8) = *(const int4*)&SB[c * 130 + hf * 64 + j * 8];
  } else if (z == 0) {
    for (int nt = 0; nt < 4; ++nt) {
      int col = n0 + wn + nt * 16 + l16;
      float bb = bq[col];
      int h = col >> 6, d = col & 63;
      for (int mt = 0; mt < 4; ++mt)
        for (int r = 0; r < 4; ++r) {
          int row = m0 + wm + mt * 16 + quad * 4 + r;
          int b_ = row >> 11, s = row & (SEQ - 1);
          qh[(((size_t)(b_ * NHEAD + h) * SEQ) + s) * DK + d] =
              f2b_rhu((acc[mt][nt][r] + bb) * QSCALE);
        }
    }
  } else {
    for (int nt = 0; nt < 4; ++nt) {
      int col = n0 + wn + nt * 16 + l16;
      int h = col >> 6, d = col & 63;
      for (int mt = 0; mt < 4; ++mt)
        for (int r = 0; r < 4; ++r) {
          int row = m0 + wm + mt * 16 + quad * 4 + r;
          int b_ = row >> 11, s = row & (SEQ - 1);
          kh[(((size_t)(b_ * NHEAD + h) * SEQ) + s) * DK + d] = f2b_rhu(acc[mt][nt][r]);
        }
    }
  }
}

// ---- output projection GEMM: 64x64 tiles, async staging in m97 halves
// geometry (row stride 32 ushorts) -- kills the 8-way fragment-read
// conflicts of the old flat stride-64 layout. ----
__global__ __launch_bounds__(256) void gemm_out_kernel(
    const unsigned short* __restrict__ A, const unsigned short* __restrict__ Bt,
    const float* __restrict__ bias, float* __restrict__ out) {
  __shared__ unsigned short As[64 * 64], Bs[64 * 64];   // halves at 0, 2048
  int bid = blockIdx.x;
  int xcd = bid & 7, slot = bid >> 3;
  int mi = slot & 7, n0 = (slot >> 3) * 64;
  int m0 = (mi * 8 + xcd) * 64;
  int t = threadIdx.x, lane = t & 63, wave = t >> 6;
  int l16 = lane & 15, quad = lane >> 4;
  int wm = (wave & 1) * 32, wn = (wave >> 1) * 32;
  f32x4 zero = {0.f, 0.f, 0.f, 0.f};
  f32x4 acc[2][2];
  for (int mt = 0; mt < 2; ++mt) for (int nt = 0; nt < 2; ++nt) acc[mt][nt] = zero;

  int drow = lane >> 2, dcol = (lane & 3) * 8;
  const unsigned short* asrc = A  + (size_t)(m0 + wave * 16 + drow) * D_MODEL + dcol;
  const unsigned short* bsrc = Bt + (size_t)(n0 + wave * 16 + drow) * D_MODEL + dcol;
  unsigned short* adst = As + wave * 512 + lane * 8;
  unsigned short* bdst = Bs + wave * 512 + lane * 8;

  for (int k0 = 0; k0 < D_MODEL; k0 += 64) {
    __syncthreads();
#pragma unroll
    for (int hf = 0; hf < 2; ++hf) {
      gll16(asrc + k0 + hf * 32, adst + hf * 2048);
      gll16(bsrc + k0 + hf * 32, bdst + hf * 2048);
    }
    __syncthreads();
#pragma unroll
    for (int half = 0; half < 2; ++half) {
      bf16x8 a[2], b[2];
      for (int mt = 0; mt < 2; ++mt)
        a[mt] = *(const bf16x8*)&As[half * 2048 + (wm + mt * 16 + l16) * 32 + quad * 8];
      for (int nt = 0; nt < 2; ++nt)
        b[nt] = *(const bf16x8*)&Bs[half * 2048 + (wn + nt * 16 + l16) * 32 + quad * 8];
      for (int mt = 0; mt < 2; ++mt)
        for (int nt = 0; nt < 2; ++nt)
          acc[mt][nt] = __builtin_amdgcn_mfma_f32_16x16x32_bf16(a[mt], b[nt], acc[mt][nt], 0, 0, 0);
    }
  }
  for (int nt = 0; nt < 2; ++nt) {
    int col = n0 + wn + nt * 16 + l16;
    float bb = bias[col];
    for (int mt = 0; mt < 2; ++mt)
      for (int r = 0; r < 4; ++r) {
        int row = m0 + wm + mt * 16 + quad * 4 + r;
        out[(size_t)row * D_MODEL + col] = acc[mt][nt][r] + bb;
      }
  }
}

// ---- flash attention. Q pre-scaled => p = exp2(s). Mask = sign-extend AND
// on packed bf16. Row-sums via MFMA ones-fragment. K/V staged by async
// global_load_lds in m97 halves geometry; P buffer aliases the dead Qs
// region (Q frags hoisted) -> LDS 25.6 KB, 4 blocks/CU resident. ----
__global__ __launch_bounds__(256) void attn_kernel(
    const unsigned short* __restrict__ qh, const unsigned short* __restrict__ kh,
    const unsigned short* __restrict__ vt, const unsigned long long* __restrict__ mbits,
    unsigned short* __restrict__ attb) {
  __shared__ unsigned short Qs[64 * 72];                 // P alias after hoist
  __shared__ unsigned short Ks[64 * 64], Vs[64 * 64];    // halves at 0, 2048
  int bid = blockIdx.x;
  int xcd = bid & 7, slot = bid >> 3;
  int bh_ = 4 * xcd + (slot >> 5);
  int qt = slot & 31;
  int b = bh_ >> 4, h = bh_ & 15;
  int t = threadIdx.x, lane = t & 63, wave = t >> 6;
  int l16 = lane & 15, quad = lane >> 4;
  size_t bh = (size_t)b * NHEAD + h;

  int sr = t >> 2, sc = (t & 3) * 8;
  const unsigned short* Qg = qh + (bh * SEQ + (size_t)qt * 64) * DK;
  *(int4*)&Qs[sr * 72 + sc]      = *(const int4*)&Qg[sr * DK + sc];
  *(int4*)&Qs[sr * 72 + sc + 32] = *(const int4*)&Qg[sr * DK + sc + 32];
  __syncthreads();
  bf16x8 qf[2];
  qf[0] = *(const bf16x8*)&Qs[(wave * 16 + l16) * 72 + quad * 8];
  qf[1] = *(const bf16x8*)&Qs[(wave * 16 + l16) * 72 + 32 + quad * 8];
  unsigned short* Pw = &Qs[wave * 1088];   // 16 rows x stride 68, aliases Qs

  const unsigned short* Kg = kh + bh * SEQ * DK;
  const unsigned short* Vg = vt + bh * DK * SEQ;
  const unsigned long long* mrow = mbits + (size_t)b * SEQ * (SEQ / 64);
  int qrow0 = qt * 64 + wave * 16 + quad * 4;

  // DMA mapping: 16 rows x 2 halves per wave; dst = uniform + lane*16B
  int drow = lane >> 2, dcol = (lane & 3) * 8;
  unsigned short* kdst = Ks + wave * 512 + lane * 8;
  unsigned short* vdst = Vs + wave * 512 + lane * 8;

  bf16x8 ones;
#pragma unroll
  for (int i = 0; i < 8; ++i) ones[i] = (short)0x3F80;

  f32x4 zero = {0.f, 0.f, 0.f, 0.f};
  f32x4 accO[4], accRS = zero;
  for (int nt = 0; nt < 4; ++nt) accO[nt] = zero;

  for (int tk = 0; tk < SEQ / 64; ++tk) {
    __syncthreads();
    {
      // K tile: rows=key (stride DK), halves over d
      const unsigned short* Kt = Kg + ((size_t)tk * 64 + wave * 16 + drow) * DK + dcol;
      // V tile: rows=d (stride SEQ), halves over key
      const unsigned short* Vt_ = Vg + (size_t)(wave * 16 + drow) * SEQ + tk * 64 + dcol;
#pragma unroll
      for (int hf = 0; hf < 2; ++hf) {
        gll16(Kt + hf * 32, kdst + hf * 2048);
        gll16(Vt_ + hf * 32, vdst + hf * 2048);
      }
    }
    __syncthreads();

    unsigned long long mw[4];
#pragma unroll
    for (int r = 0; r < 4; ++r)
      mw[r] = mrow[(size_t)(qrow0 + r) * (SEQ / 64) + tk] >> l16;

    f32x4 accS[4];
    for (int nt = 0; nt < 4; ++nt) accS[nt] = zero;
#pragma unroll
    for (int step = 0; step < 2; ++step)
      for (int nt = 0; nt < 4; ++nt) {
        bf16x8 bk = *(const bf16x8*)&Ks[step * 2048 + (nt * 16 + l16) * 32 + quad * 8];
        accS[nt] = __builtin_amdgcn_mfma_f32_16x16x32_bf16(qf[step], bk, accS[nt], 0, 0, 0);
      }

#pragma unroll
    for (int r = 0; r < 4; ++r) {
      unsigned lo = (unsigned)mw[r], hi = (unsigned)(mw[r] >> 32);
#pragma unroll
      for (int nt = 0; nt < 4; ++nt) {
        unsigned halfw = (nt < 2) ? lo : hi;
        const int sh = 31 - ((nt & 1) * 16);
        float pv = __builtin_amdgcn_exp2f(accS[nt][r]);
        unsigned u = (__builtin_bit_cast(unsigned, pv) + 0x8000u) >> 16;
        int mskv = ((int)(halfw << sh)) >> 31;
        Pw[(quad * 4 + r) * 68 + nt * 16 + l16] = (unsigned short)(u & (unsigned)mskv);
      }
    }

#pragma unroll
    for (int step = 0; step < 2; ++step) {
      short4 plo = *(const short4*)&Pw[l16 * 68 + step * 32 + quad * 8];
      short4 phi = *(const short4*)&Pw[l16 * 68 + step * 32 + quad * 8 + 4];
      bf16x8 ap = {plo.x, plo.y, plo.z, plo.w, phi.x, phi.y, phi.z, phi.w};
      accRS = __builtin_amdgcn_mfma_f32_16x16x32_bf16(ap, ones, accRS, 0, 0, 0);
      for (int nt = 0; nt < 4; ++nt) {
        bf16x8 bv_ = *(const bf16x8*)&Vs[step * 2048 + (nt * 16 + l16) * 32 + quad * 8];
        accO[nt] = __builtin_amdgcn_mfma_f32_16x16x32_bf16(ap, bv_, accO[nt], 0, 0, 0);
      }
    }
  }

  for (int r = 0; r < 4; ++r) {
    float sden = accRS[r];
    float inv = sden > 0.f ? 1.f / sden : 0.f;
    int row = qt * 64 + wave * 16 + quad * 4 + r;
    size_t ob = ((size_t)b * SEQ + row) * D_MODEL + (size_t)h * DK;
    for (int nt = 0; nt < 4; ++nt)
      attb[ob + nt * 16 + l16] = f2b_rhu(accO[nt][r] * inv);
  }
}

extern "C" void kernel_launch(void* const* d_in, const int* in_sizes, int n_in,
                              void* d_out, int out_size, void* d_ws, size_t ws_size,
                              hipStream_t stream) {
  (void)in_sizes; (void)n_in; (void)out_size; (void)ws_size;
  const float* q    = (const float*)d_in[0];
  const float* k    = (const float*)d_in[1];
  const float* v    = (const float*)d_in[2];
  const int*   mask = (const int*)d_in[3];
  const float* wq   = (const float*)d_in[4];
  const float* bq   = (const float*)d_in[5];
  const float* wk   = (const float*)d_in[6];
  const float* wv   = (const float*)d_in[7];
  const float* bv   = (const float*)d_in[8];
  const float* wf   = (const float*)d_in[9];
  const float* bf   = (const float*)d_in[10];

  char* ws = (char*)d_ws;
  // workspace layout (bytes) -- ~44.7 MiB total (proven safe; 76.5 known bad).
  // d_out (16 MiB fp32, only read after gemm_out) doubles as scratch for
  // q_bf16 + k_bf16; wqt/wkt/wvt dead after gemm_qkv so attb aliases them.
  unsigned short* wft  = (unsigned short*)(ws + 0);          // 2 MiB, live till end
  unsigned short* wqt  = (unsigned short*)(ws + 2097152);    // 2 MiB
  unsigned short* wkt  = (unsigned short*)(ws + 4194304);    // 2 MiB
  unsigned short* wvt  = (unsigned short*)(ws + 6291456);    // 2 MiB
  unsigned short* attb = (unsigned short*)(ws + 2097152);    // 8 MiB alias
  unsigned short* qhp  = (unsigned short*)(ws + 10485760);   // 8 MiB
  unsigned short* khp  = (unsigned short*)(ws + 18874368);   // 8 MiB
  unsigned short* vtp  = (unsigned short*)(ws + 27262976);   // 8 MiB
  unsigned long long* mbits = (unsigned long long*)(ws + 35651584); // 1 MiB
  unsigned short* vb   = (unsigned short*)(ws + 36700160);   // 8 MiB
  unsigned short* qb   = (unsigned short*)d_out;             // 8 MiB (d_out scratch)
  unsigned short* kb   = (unsigned short*)d_out + 4194304;   // 8 MiB

  hipLaunchKernelGGL(cast3_kernel, dim3(2048, 3), dim3(256), 0, stream, q, k, v, qb, kb, vb);
  hipLaunchKernelGGL(wtrans_kernel, dim3(16, 16, 4), dim3(256), 0, stream,
                     wq, wk, wv, wf, wqt, wkt, wvt, wft);
  hipLaunchKernelGGL(maskpack_kernel, dim3(32768), dim3(256), 0, stream, mask, mbits);
  hipLaunchKernelGGL(gemm_qkv_kernel, dim3(768), dim3(256), 0, stream,
                     qb, kb, vb, wqt, wkt, wvt, bq, bv, qhp, khp, vtp);
  hipLaunchKernelGGL(attn_kernel, dim3(1024), dim3(256), 0, stream,
                     qhp, khp, vtp, mbits, attb);
  hipLaunchKernelGGL(gemm_out_kernel, dim3(1024), dim3(256), 0, stream,
                     attb, wft, bf, (float*)d_out);
}

// Round 10
// 295.150 us; speedup vs baseline: 1.6713x; 1.0184x over previous
//
#include <hip/hip_runtime.h>

// ---- problem constants ----
#define D_MODEL 1024
#define NHEAD   16
#define DK      64
#define BATCH   2
#define SEQ     2048

typedef __attribute__((ext_vector_type(8))) short bf16x8;
typedef __attribute__((ext_vector_type(4))) float f32x4;

#define QSCALE 0.18033688011f   // log2(e) / sqrt(64): folded into Q projection

__device__ __forceinline__ unsigned short f2b(float x) {
  unsigned u = __builtin_bit_cast(unsigned, x);
  u = (u + 0x7fffu + ((u >> 16) & 1u)) >> 16;   // RNE to bf16
  return (unsigned short)u;
}
// round-half-up bf16 (bias 2^-17 rel, error <= 2^-9 like RNE) -- 1 add
__device__ __forceinline__ unsigned short f2b_rhu(float x) {
  return (unsigned short)((__builtin_bit_cast(unsigned, x) + 0x8000u) >> 16);
}
// pack two fp32 -> two bf16 (round-half-up) in 3 VALU: add, add, v_perm
__device__ __forceinline__ int pk2(float a, float b) {
  unsigned ua = __builtin_bit_cast(unsigned, a) + 0x8000u;
  unsigned ub = __builtin_bit_cast(unsigned, b) + 0x8000u;
  return (int)__builtin_amdgcn_perm(ub, ua, 0x07060302u);  // [ub.hi16 : ua.hi16]
}

// async 16B global->LDS (m97 pattern). LDS dest = wave-uniform base + lane*16.
typedef const __attribute__((address_space(1))) void* gas_p;
typedef __attribute__((address_space(3))) void* las_p;
__device__ __forceinline__ void gll16(const void* g, void* l) {
  __builtin_amdgcn_global_load_lds((gas_p)g, (las_p)l, 16, 0, 0);
}

// ---- cast q,k,v fp32 -> bf16 (qb/kb live in d_out scratch, vb in ws) ----
__global__ __launch_bounds__(256) void cast3_kernel(
    const float* __restrict__ q, const float* __restrict__ k, const float* __restrict__ v,
    unsigned short* __restrict__ qb, unsigned short* __restrict__ kb,
    unsigned short* __restrict__ vb) {
  const float* src = blockIdx.y == 0 ? q : (blockIdx.y == 1 ? k : v);
  unsigned short* dst = blockIdx.y == 0 ? qb : (blockIdx.y == 1 ? kb : vb);
  size_t i = ((size_t)blockIdx.x * 256 + threadIdx.x) * 8;
  float4 x0 = *(const float4*)&src[i];
  float4 x1 = *(const float4*)&src[i + 4];
  int4 w;
  w.x = pk2(x0.x, x0.y); w.y = pk2(x0.z, x0.w);
  w.z = pk2(x1.x, x1.y); w.w = pk2(x1.z, x1.w);
  *(int4*)&dst[i] = w;
}

// ---- transpose + cast weights: w[in][out] fp32 -> wt[out][in] bf16 ----
__global__ __launch_bounds__(256) void wtrans_kernel(
    const float* __restrict__ wq, const float* __restrict__ wk,
    const float* __restrict__ wv, const float* __restrict__ wf,
    unsigned short* __restrict__ wqt, unsigned short* __restrict__ wkt,
    unsigned short* __restrict__ wvt, unsigned short* __restrict__ wft) {
  __shared__ float tile[64][65];
  const float* w; unsigned short* wt;
  switch (blockIdx.z) {
    case 0: w = wq; wt = wqt; break;
    case 1: w = wk; wt = wkt; break;
    case 2: w = wv; wt = wvt; break;
    default: w = wf; wt = wft; break;
  }
  int r0 = blockIdx.y * 64, c0 = blockIdx.x * 64;
  int t = threadIdx.x;
  for (int i = 0; i < 16; ++i) {
    int idx = t + i * 256; int r = idx >> 6, c = idx & 63;
    tile[r][c] = w[(size_t)(r0 + r) * D_MODEL + c0 + c];
  }
  __syncthreads();
  for (int i = 0; i < 16; ++i) {
    int idx = t + i * 256; int r = idx >> 6, c = idx & 63;
    wt[(size_t)(c0 + r) * D_MODEL + r0 + c] = f2b(tile[c][r]);
  }
}

// ---- pack mask int32 -> bit-words (bit lane = mask!=0), one u64 per 64 keys ----
__global__ __launch_bounds__(256) void maskpack_kernel(
    const int* __restrict__ mask, unsigned long long* __restrict__ mbits) {
  size_t gw = ((size_t)blockIdx.x * 256 + threadIdx.x) >> 6;
  int lane = threadIdx.x & 63;
  int val = mask[gw * 64 + lane];
  unsigned long long bits = __ballot(val != 0);
  if (lane == 0) mbits[gw] = bits;
}

// ---- fused QKV projection GEMM: 128x128 tile, BK=32, DOUBLE-BUFFERED
// async staging with ONE barrier per iteration: DMA for chunk it+1 is issued
// right after the barrier opening iteration it, and drained a full compute
// phase later by the next barrier (kills the R6-R9 98us drain stall). ----
__global__ __launch_bounds__(256) void gemm_qkv_kernel(
    const unsigned short* __restrict__ qb, const unsigned short* __restrict__ kb,
    const unsigned short* __restrict__ vb,
    const unsigned short* __restrict__ wqt, const unsigned short* __restrict__ wkt,
    const unsigned short* __restrict__ wvt,
    const float* __restrict__ bq, const float* __restrict__ bv,
    unsigned short* __restrict__ qh, unsigned short* __restrict__ kh,
    unsigned short* __restrict__ vt) {
  // buffers: buf b at b*8192 (As at +0, Bs at +4096, each 128 rows x 32 cols);
  // V-transpose epilogue aliases the whole 16640-short region.
  __shared__ unsigned short SB[16640];
  int bid = blockIdx.x;
  int xcd = bid & 7, slot = bid >> 3;      // 96 slots per XCD
  int mi = slot & 3, zn = slot >> 2;       // 4 m-panels per XCD, zn in [0,24)
  int z = zn >> 3;
  int n0 = (zn & 7) * 128;
  int m0 = (mi * 8 + xcd) * 128;
  const unsigned short* A; const unsigned short* Bt;
  switch (z) {
    case 0:  A = qb; Bt = wqt; break;
    case 1:  A = kb; Bt = wkt; break;
    default: A = vb; Bt = wvt; break;
  }
  int t = threadIdx.x, lane = t & 63, wave = t >> 6;
  int l16 = lane & 15, quad = lane >> 4;
  int wm = (wave & 1) * 64, wn = (wave >> 1) * 64;
  f32x4 zero = {0.f, 0.f, 0.f, 0.f};
  f32x4 acc[4][4];
  for (int mt = 0; mt < 4; ++mt) for (int nt = 0; nt < 4; ++nt) acc[mt][nt] = zero;

  int drow = lane >> 2, dcol = (lane & 3) * 8;
  const unsigned short* asrc = A  + (size_t)(m0 + wave * 32 + drow) * D_MODEL + dcol;
  const unsigned short* bsrc = Bt + (size_t)(n0 + wave * 32 + drow) * D_MODEL + dcol;
  int dst = wave * 1024 + lane * 8;        // within-buffer wave slice (+g*512)

  // prologue: chunk 0 -> buf0
#pragma unroll
  for (int g = 0; g < 2; ++g) {
    gll16(asrc + (size_t)(g * 16) * D_MODEL, &SB[dst + g * 512]);
    gll16(bsrc + (size_t)(g * 16) * D_MODEL, &SB[4096 + dst + g * 512]);
  }
  for (int it = 0; it < 32; ++it) {
    __syncthreads();                       // drains chunk it's DMAs
    if (it + 1 < 32) {
      int nb = ((it + 1) & 1) * 8192, kn = (it + 1) * 32;
#pragma unroll
      for (int g = 0; g < 2; ++g) {
        gll16(asrc + (size_t)(g * 16) * D_MODEL + kn, &SB[nb + dst + g * 512]);
        gll16(bsrc + (size_t)(g * 16) * D_MODEL + kn, &SB[nb + 4096 + dst + g * 512]);
      }
    }
    int cb = (it & 1) * 8192;
    bf16x8 a[4], b[4];
    for (int mt = 0; mt < 4; ++mt)
      a[mt] = *(const bf16x8*)&SB[cb + (wm + mt * 16 + l16) * 32 + quad * 8];
    for (int nt = 0; nt < 4; ++nt)
      b[nt] = *(const bf16x8*)&SB[cb + 4096 + (wn + nt * 16 + l16) * 32 + quad * 8];
    for (int mt = 0; mt < 4; ++mt)
      for (int nt = 0; nt < 4; ++nt)
        acc[mt][nt] = __builtin_amdgcn_mfma_f32_16x16x32_bf16(a[mt], b[nt], acc[mt][nt], 0, 0, 0);
  }

  if (z == 2) {
    __syncthreads();
#pragma unroll
    for (int nt = 0; nt < 4; ++nt) {
      int col = wn + nt * 16 + l16;
      float bb = bv[n0 + col];
      for (int mt = 0; mt < 4; ++mt)
        for (int r = 0; r < 4; ++r)
          SB[col * 130 + wm + mt * 16 + quad * 4 + r] = f2b_rhu(acc[mt][nt][r] + bb);
    }
    __syncthreads();
    int c = t >> 1, hf = t & 1;
    int colg = n0 + c, hh = colg >> 6, dd = colg & 63;
    int b_ = m0 >> 11, sbase = m0 & (SEQ - 1);
    unsigned short* dstp = vt + (((size_t)(b_ * NHEAD + hh)) * DK + dd) * SEQ + sbase + hf * 64;
#pragma unroll
    for (int j = 0; j < 8; ++j)
      *(int4*)(dstp + j * 8) = *(const int4*)&SB[c * 130 + hf * 64 + j * 8];
  } else if (z == 0) {
    for (int nt = 0; nt < 4; ++nt) {
      int col = n0 + wn + nt * 16 + l16;
      float bb = bq[col];
      int h = col >> 6, d = col & 63;
      for (int mt = 0; mt < 4; ++mt)
        for (int r = 0; r < 4; ++r) {
          int row = m0 + wm + mt * 16 + quad * 4 + r;
          int b_ = row >> 11, s = row & (SEQ - 1);
          qh[(((size_t)(b_ * NHEAD + h) * SEQ) + s) * DK + d] =
              f2b_rhu((acc[mt][nt][r] + bb) * QSCALE);
        }
    }
  } else {
    for (int nt = 0; nt < 4; ++nt) {
      int col = n0 + wn + nt * 16 + l16;
      int h = col >> 6, d = col & 63;
      for (int mt = 0; mt < 4; ++mt)
        for (int r = 0; r < 4; ++r) {
          int row = m0 + wm + mt * 16 + quad * 4 + r;
          int b_ = row >> 11, s = row & (SEQ - 1);
          kh[(((size_t)(b_ * NHEAD + h) * SEQ) + s) * DK + d] = f2b_rhu(acc[mt][nt][r]);
        }
    }
  }
}

// ---- output projection GEMM: 64x64 tiles, BK=64 double-buffered,
// one barrier per iteration (same issue-early/drain-late scheme). ----
__global__ __launch_bounds__(256) void gemm_out_kernel(
    const unsigned short* __restrict__ A, const unsigned short* __restrict__ Bt,
    const float* __restrict__ bias, float* __restrict__ out) {
  __shared__ unsigned short As[8192], Bs[8192];   // buf b at b*4096, halves at +0,+2048
  int bid = blockIdx.x;
  int xcd = bid & 7, slot = bid >> 3;
  int mi = slot & 7, n0 = (slot >> 3) * 64;
  int m0 = (mi * 8 + xcd) * 64;
  int t = threadIdx.x, lane = t & 63, wave = t >> 6;
  int l16 = lane & 15, quad = lane >> 4;
  int wm = (wave & 1) * 32, wn = (wave >> 1) * 32;
  f32x4 zero = {0.f, 0.f, 0.f, 0.f};
  f32x4 acc[2][2];
  for (int mt = 0; mt < 2; ++mt) for (int nt = 0; nt < 2; ++nt) acc[mt][nt] = zero;

  int drow = lane >> 2, dcol = (lane & 3) * 8;
  const unsigned short* asrc = A  + (size_t)(m0 + wave * 16 + drow) * D_MODEL + dcol;
  const unsigned short* bsrc = Bt + (size_t)(n0 + wave * 16 + drow) * D_MODEL + dcol;
  int dst = wave * 512 + lane * 8;

#pragma unroll
  for (int hf = 0; hf < 2; ++hf) {
    gll16(asrc + hf * 32, &As[dst + hf * 2048]);
    gll16(bsrc + hf * 32, &Bs[dst + hf * 2048]);
  }
  for (int it = 0; it < 16; ++it) {
    __syncthreads();
    if (it + 1 < 16) {
      int nb = ((it + 1) & 1) * 4096, kn = (it + 1) * 64;
#pragma unroll
      for (int hf = 0; hf < 2; ++hf) {
        gll16(asrc + kn + hf * 32, &As[nb + dst + hf * 2048]);
        gll16(bsrc + kn + hf * 32, &Bs[nb + dst + hf * 2048]);
      }
    }
    int cb = (it & 1) * 4096;
#pragma unroll
    for (int half = 0; half < 2; ++half) {
      bf16x8 a[2], b[2];
      for (int mt = 0; mt < 2; ++mt)
        a[mt] = *(const bf16x8*)&As[cb + half * 2048 + (wm + mt * 16 + l16) * 32 + quad * 8];
      for (int nt = 0; nt < 2; ++nt)
        b[nt] = *(const bf16x8*)&Bs[cb + half * 2048 + (wn + nt * 16 + l16) * 32 + quad * 8];
      for (int mt = 0; mt < 2; ++mt)
        for (int nt = 0; nt < 2; ++nt)
          acc[mt][nt] = __builtin_amdgcn_mfma_f32_16x16x32_bf16(a[mt], b[nt], acc[mt][nt], 0, 0, 0);
    }
  }
  for (int nt = 0; nt < 2; ++nt) {
    int col = n0 + wn + nt * 16 + l16;
    float bb = bias[col];
    for (int mt = 0; mt < 2; ++mt)
      for (int r = 0; r < 4; ++r) {
        int row = m0 + wm + mt * 16 + quad * 4 + r;
        out[(size_t)row * D_MODEL + col] = acc[mt][nt][r] + bb;
      }
  }
}

// ---- flash attention, pipelined staging:
//   K double-buffered: DMA K(t+1) issued at iter top, drained by next top.
//   V single-buffered: DMA V(t) issued at iter top, drained by the mid
//   barrier (overlaps S-MFMA + softmax); PV reads after mid barrier.
//   Q fragments loaded straight from global (no Q LDS); P in own region.
// LDS 32.5 KB -> 4 blocks/CU. Q pre-scaled => p=exp2(s); mask = sext-AND;
// row-sums via MFMA ones-fragment. ----
__global__ __launch_bounds__(256) void attn_kernel(
    const unsigned short* __restrict__ qh, const unsigned short* __restrict__ kh,
    const unsigned short* __restrict__ vt, const unsigned long long* __restrict__ mbits,
    unsigned short* __restrict__ attb) {
  __shared__ unsigned short Ks[8192];   // buf b at b*4096, halves at +0,+2048
  __shared__ unsigned short Vs[4096];   // halves at +0,+2048
  __shared__ unsigned short Ps[4352];   // 4 waves x 16 rows x stride 68
  int bid = blockIdx.x;
  int xcd = bid & 7, slot = bid >> 3;
  int bh_ = 4 * xcd + (slot >> 5);
  int qt = slot & 31;
  int b = bh_ >> 4, h = bh_ & 15;
  int t = threadIdx.x, lane = t & 63, wave = t >> 6;
  int l16 = lane & 15, quad = lane >> 4;
  size_t bh = (size_t)b * NHEAD + h;

  // Q fragments straight from global (one row per l16-lane, 2x16B)
  const unsigned short* Qg = qh + (bh * SEQ + (size_t)(qt * 64 + wave * 16 + l16)) * DK;
  bf16x8 qf[2];
  qf[0] = *(const bf16x8*)&Qg[quad * 8];
  qf[1] = *(const bf16x8*)&Qg[32 + quad * 8];
  unsigned short* Pw = &Ps[wave * 1088];

  const unsigned short* Kg = kh + bh * SEQ * DK;
  const unsigned short* Vg = vt + bh * DK * SEQ;
  const unsigned long long* mrow = mbits + (size_t)b * SEQ * (SEQ / 64);
  int qrow0 = qt * 64 + wave * 16 + quad * 4;

  int drow = lane >> 2, dcol = (lane & 3) * 8;
  int dst = wave * 512 + lane * 8;
  const unsigned short* Vrow = Vg + (size_t)(wave * 16 + drow) * SEQ + dcol;

  bf16x8 ones;
#pragma unroll
  for (int i = 0; i < 8; ++i) ones[i] = (short)0x3F80;

  f32x4 zero = {0.f, 0.f, 0.f, 0.f};
  f32x4 accO[4], accRS = zero;
  for (int nt = 0; nt < 4; ++nt) accO[nt] = zero;

  // prologue: K tile 0 -> Kbuf0
  {
    const unsigned short* Kt = Kg + (size_t)(wave * 16 + drow) * DK + dcol;
#pragma unroll
    for (int hf = 0; hf < 2; ++hf) gll16(Kt + hf * 32, &Ks[dst + hf * 2048]);
  }

  for (int tk = 0; tk < SEQ / 64; ++tk) {
    __syncthreads();   // drains K(tk); all waves done PV(tk-1) & P reads
    // issue K(tk+1) into the other K buffer
    if (tk + 1 < SEQ / 64) {
      int nb = ((tk + 1) & 1) * 4096;
      const unsigned short* Kt = Kg + (size_t)((tk + 1) * 64 + wave * 16 + drow) * DK + dcol;
#pragma unroll
      for (int hf = 0; hf < 2; ++hf) gll16(Kt + hf * 32, &Ks[nb + dst + hf * 2048]);
    }
    // issue V(tk) into the single V buffer (drained by the mid barrier)
#pragma unroll
    for (int hf = 0; hf < 2; ++hf) gll16(Vrow + tk * 64 + hf * 32, &Vs[dst + hf * 2048]);

    unsigned long long mw[4];
#pragma unroll
    for (int r = 0; r < 4; ++r)
      mw[r] = mrow[(size_t)(qrow0 + r) * (SEQ / 64) + tk] >> l16;

    // S = Q K^T from current K buffer
    int cb = (tk & 1) * 4096;
    f32x4 accS[4];
    for (int nt = 0; nt < 4; ++nt) accS[nt] = zero;
#pragma unroll
    for (int step = 0; step < 2; ++step)
      for (int nt = 0; nt < 4; ++nt) {
        bf16x8 bk = *(const bf16x8*)&Ks[cb + step * 2048 + (nt * 16 + l16) * 32 + quad * 8];
        accS[nt] = __builtin_amdgcn_mfma_f32_16x16x32_bf16(qf[step], bk, accS[nt], 0, 0, 0);
      }

    // p = exp2(s) masked, packed to bf16 in registers
    unsigned short pb[4][4];
#pragma unroll
    for (int r = 0; r < 4; ++r) {
      unsigned lo = (unsigned)mw[r], hi = (unsigned)(mw[r] >> 32);
#pragma unroll
      for (int nt = 0; nt < 4; ++nt) {
        unsigned halfw = (nt < 2) ? lo : hi;
        const int sh = 31 - ((nt & 1) * 16);
        float pv = __builtin_amdgcn_exp2f(accS[nt][r]);
        unsigned u = (__builtin_bit_cast(unsigned, pv) + 0x8000u) >> 16;
        int mskv = ((int)(halfw << sh)) >> 31;
        pb[r][nt] = (unsigned short)(u & (unsigned)mskv);
      }
    }

    __syncthreads();   // drains V(tk) (K(tk+1) drains early too); S reads done
#pragma unroll
    for (int r = 0; r < 4; ++r)
#pragma unroll
      for (int nt = 0; nt < 4; ++nt)
        Pw[(quad * 4 + r) * 68 + nt * 16 + l16] = pb[r][nt];

    // O += P V ; row-sums += P * ones
#pragma unroll
    for (int step = 0; step < 2; ++step) {
      short4 plo = *(const short4*)&Pw[l16 * 68 + step * 32 + quad * 8];
      short4 phi = *(const short4*)&Pw[l16 * 68 + step * 32 + quad * 8 + 4];
      bf16x8 ap = {plo.x, plo.y, plo.z, plo.w, phi.x, phi.y, phi.z, phi.w};
      accRS = __builtin_amdgcn_mfma_f32_16x16x32_bf16(ap, ones, accRS, 0, 0, 0);
      for (int nt = 0; nt < 4; ++nt) {
        bf16x8 bv_ = *(const bf16x8*)&Vs[step * 2048 + (nt * 16 + l16) * 32 + quad * 8];
        accO[nt] = __builtin_amdgcn_mfma_f32_16x16x32_bf16(ap, bv_, accO[nt], 0, 0, 0);
      }
    }
  }

  for (int r = 0; r < 4; ++r) {
    float sden = accRS[r];
    float inv = sden > 0.f ? 1.f / sden : 0.f;
    int row = qt * 64 + wave * 16 + quad * 4 + r;
    size_t ob = ((size_t)b * SEQ + row) * D_MODEL + (size_t)h * DK;
    for (int nt = 0; nt < 4; ++nt)
      attb[ob + nt * 16 + l16] = f2b_rhu(accO[nt][r] * inv);
  }
}

extern "C" void kernel_launch(void* const* d_in, const int* in_sizes, int n_in,
                              void* d_out, int out_size, void* d_ws, size_t ws_size,
                              hipStream_t stream) {
  (void)in_sizes; (void)n_in; (void)out_size; (void)ws_size;
  const float* q    = (const float*)d_in[0];
  const float* k    = (const float*)d_in[1];
  const float* v    = (const float*)d_in[2];
  const int*   mask = (const int*)d_in[3];
  const float* wq   = (const float*)d_in[4];
  const float* bq   = (const float*)d_in[5];
  const float* wk   = (const float*)d_in[6];
  const float* wv   = (const float*)d_in[7];
  const float* bv   = (const float*)d_in[8];
  const float* wf   = (const float*)d_in[9];
  const float* bf   = (const float*)d_in[10];

  char* ws = (char*)d_ws;
  // workspace layout (bytes) -- ~44.7 MiB total (proven safe; 76.5 known bad).
  // d_out (16 MiB fp32, only read after gemm_out) doubles as scratch for
  // q_bf16 + k_bf16; wqt/wkt/wvt dead after gemm_qkv so attb aliases them.
  unsigned short* wft  = (unsigned short*)(ws + 0);          // 2 MiB, live till end
  unsigned short* wqt  = (unsigned short*)(ws + 2097152);    // 2 MiB
  unsigned short* wkt  = (unsigned short*)(ws + 4194304);    // 2 MiB
  unsigned short* wvt  = (unsigned short*)(ws + 6291456);    // 2 MiB
  unsigned short* attb = (unsigned short*)(ws + 2097152);    // 8 MiB alias
  unsigned short* qhp  = (unsigned short*)(ws + 10485760);   // 8 MiB
  unsigned short* khp  = (unsigned short*)(ws + 18874368);   // 8 MiB
  unsigned short* vtp  = (unsigned short*)(ws + 27262976);   // 8 MiB
  unsigned long long* mbits = (unsigned long long*)(ws + 35651584); // 1 MiB
  unsigned short* vb   = (unsigned short*)(ws + 36700160);   // 8 MiB
  unsigned short* qb   = (unsigned short*)d_out;             // 8 MiB (d_out scratch)
  unsigned short* kb   = (unsigned short*)d_out + 4194304;   // 8 MiB

  hipLaunchKernelGGL(cast3_kernel, dim3(2048, 3), dim3(256), 0, stream, q, k, v, qb, kb, vb);
  hipLaunchKernelGGL(wtrans_kernel, dim3(16, 16, 4), dim3(256), 0, stream,
                     wq, wk, wv, wf, wqt, wkt, wvt, wft);
  hipLaunchKernelGGL(maskpack_kernel, dim3(32768), dim3(256), 0, stream, mask, mbits);
  hipLaunchKernelGGL(gemm_qkv_kernel, dim3(768), dim3(256), 0, stream,
                     qb, kb, vb, wqt, wkt, wvt, bq, bv, qhp, khp, vtp);
  hipLaunchKernelGGL(attn_kernel, dim3(1024), dim3(256), 0, stream,
                     qhp, khp, vtp, mbits, attb);
  hipLaunchKernelGGL(gemm_out_kernel, dim3(1024), dim3(256), 0, stream,
                     attb, wft, bf, (float*)d_out);
}